// Round 11
// baseline (1249.278 us; speedup 1.0000x reference)
//
#include <hip/hip_runtime.h>
#include <cstdint>
#include <cstddef>

#define TSTEPS 60
#define NB 4096
#define HD 128

typedef __attribute__((ext_vector_type(8))) short short8;
typedef __attribute__((ext_vector_type(4))) float f32x4;

// ---------------- workspace layout (byte offsets) ----------------
#define WS_SJ    0
#define WS_SI    16384
#define WS_HID   32768                 // 4096*128 f32 = 2 MB
#define WS_HTH   2129920               // hid^T hi bf16 [128][4096] = 1 MB
#define WS_HTL   3178496               // hid^T lo bf16 = 1 MB
#define WS_F0H   4227072               // wih0 hi frags 49152 B
#define WS_F0L   (WS_F0H+49152)
#define WS_FR0H  (WS_F0L+49152)        // whh0 hi 98304 B
#define WS_FR0L  (WS_FR0H+98304)
#define WS_FR1H  (WS_FR0L+98304)
#define WS_FR1L  (WS_FR1H+98304)
#define WS_FR2H  (WS_FR1L+98304)
#define WS_FR2L  (WS_FR2H+98304)
#define WS_NEED  (WS_FR2L+98304)

__device__ __forceinline__ float b2f(unsigned short h){ return __uint_as_float(((unsigned)h)<<16); }
__device__ __forceinline__ unsigned short f2b(float f){
  unsigned u = __float_as_uint(f);
  u = (u + 0x7FFFu + ((u>>16)&1u)) >> 16;
  return (unsigned short)u;
}
__device__ __forceinline__ float sigm(float x){ return 1.0f/(1.0f + __expf(-x)); }
__device__ __forceinline__ float tanhfast(float x){
  float xc = fminf(fmaxf(x,-15.0f),15.0f);
  float e = __expf(2.0f*xc);
  return (e-1.0f)/(e+1.0f);
}
__device__ __forceinline__ float lrelu(float x){ return x > 0.0f ? x : 0.01f*x; }
__device__ __forceinline__ float ldr1(const void* p, size_t i, int f32){
  return f32 ? ((const float*)p)[i] : b2f(((const unsigned short*)p)[i]);
}
template<bool F32>
__device__ __forceinline__ float4 ldg4c(const void* p, size_t i){
  if (F32) return *(const float4*)((const float*)p + i);
  ushort4 u = *(const ushort4*)((const unsigned short*)p + i);
  float4 f; f.x=b2f(u.x); f.y=b2f(u.y); f.z=b2f(u.z); f.w=b2f(u.w); return f;
}
__device__ __forceinline__ f32x4 f4zero(){ f32x4 v = {0.f,0.f,0.f,0.f}; return v; }

// Pin a value in registers (use+def): rematerialization from memory illegal.
__device__ __forceinline__ void pinv(short8& v){ asm volatile("" : "+v"(v)); }

// Block-uniform dtype probe (validated R7/R8): 1 = fp32, 0 = bf16.
__device__ int probe_f32(const void* p, int nprobe, volatile int* s){
  if (threadIdx.x == 0) *s = 0;
  __syncthreads();
  if ((int)threadIdx.x < nprobe) {
    float v = b2f(((const unsigned short*)p)[threadIdx.x]);
    if (!(v == v) || fabsf(v) > 1e4f) *s = 1;
  }
  __syncthreads();
  int r = *s;
  __syncthreads();
  return r;
}

__global__ void diag_kernel(float* out, float code){
  int i = blockIdx.x*256 + threadIdx.x;
  if (i < 4096) out[i] = code;
}

// ---------------- weight repack (validated R8) ----------------------------
__device__ void repack_mat(const void* src, int f32, int K, int nks,
                           unsigned short* hi, unsigned short* lo,
                           int tid, int nthr){
  int total = 384*K;
  for (int idx = tid; idx < total; idx += nthr) {
    int j = idx & 7, lane = (idx>>3)&63, t = idx>>9;
    int ks = t % nks, g = (t/nks)%3, w = t/(nks*3);
    int row = 16*(w + 8*g) + (lane & 15);
    int k   = ks*32 + ((lane>>4)<<3) + j;
    float v = f32 ? ((const float*)src)[(size_t)row*K + k]
                  : b2f(((const unsigned short*)src)[(size_t)row*K + k]);
    unsigned short h = f2b(v);
    hi[idx] = h;
    lo[idx] = f2b(v - b2f(h));
  }
}

__global__ __launch_bounds__(256) void repack_kernel(
    const void* wih0, const void* whh0, const void* wih1, const void* whh1,
    char* ws)
{
  __shared__ int sp;
  int f0 = probe_f32(wih0, 256, &sp);
  int f1 = probe_f32(whh0, 256, &sp);
  int f2 = probe_f32(wih1, 256, &sp);
  int f3 = probe_f32(whh1, 256, &sp);
  int tid  = blockIdx.x*256 + threadIdx.x;
  int nthr = gridDim.x*256;
  repack_mat(wih0, f0,  64, 2, (unsigned short*)(ws+WS_F0H),  (unsigned short*)(ws+WS_F0L),  tid, nthr);
  repack_mat(whh0, f1, 128, 4, (unsigned short*)(ws+WS_FR0H), (unsigned short*)(ws+WS_FR0L), tid, nthr);
  repack_mat(wih1, f2, 128, 4, (unsigned short*)(ws+WS_FR1H), (unsigned short*)(ws+WS_FR1L), tid, nthr);
  repack_mat(whh1, f3, 128, 4, (unsigned short*)(ws+WS_FR2H), (unsigned short*)(ws+WS_FR2L), tid, nthr);
}

// ---------------- MFMA GRU: batched lo streams, pinned hi, 16 rows/block --
// acc[0]=r(i+h), acc[1]=z(i+h), acc[2]=i_n, acc[3]=h_n.
#define MFMA __builtin_amdgcn_mfma_f32_16x16x32_bf16

__global__ __launch_bounds__(512, 1) void gru_kernel(
    const void* __restrict__ xg,
    const void* __restrict__ bih0, const void* __restrict__ bhh0,
    const void* __restrict__ bih1, const void* __restrict__ bhh1,
    const char* __restrict__ ws, float* __restrict__ hidg,
    unsigned short* __restrict__ hTh, unsigned short* __restrict__ hTl)
{
  __shared__ __align__(16) unsigned short wih0L[49152];              // hi | lo
  __shared__ __align__(16) unsigned short xhi[1152], xlo[1152];      // 16x72
  __shared__ __align__(16) unsigned short h0hi[2176], h0lo[2176];    // 16x136
  __shared__ __align__(16) unsigned short h1hi[2176], h1lo[2176];
  __shared__ int sp;
  const int tid  = threadIdx.x;
  const int w    = tid >> 6;
  const int lane = tid & 63;
  const int ln   = lane & 15;
  const int kq   = lane >> 4;
  const int r0   = blockIdx.x * 16;

  int xf  = probe_f32(xg,   256, &sp);
  int fb0 = probe_f32(bih0, 256, &sp);
  int fh0 = probe_f32(bhh0, 256, &sp);
  int fb1 = probe_f32(bih1, 256, &sp);
  int fh1 = probe_f32(bhh1, 256, &sp);

  const unsigned short* f0h  = (const unsigned short*)(ws+WS_F0H);
  const unsigned short* f0l  = (const unsigned short*)(ws+WS_F0L);
  const unsigned short* fr0h = (const unsigned short*)(ws+WS_FR0H);
  const unsigned short* fr0l = (const unsigned short*)(ws+WS_FR0L);
  const unsigned short* fr1h = (const unsigned short*)(ws+WS_FR1H);
  const unsigned short* fr1l = (const unsigned short*)(ws+WS_FR1L);
  const unsigned short* fr2h = (const unsigned short*)(ws+WS_FR2H);
  const unsigned short* fr2l = (const unsigned short*)(ws+WS_FR2L);

  // stage wih0 hi+lo into LDS (step-invariant)
  for (int i = tid*8; i < 24576; i += 512*8) {
    *(ushort4*)&wih0L[i]         = *(const ushort4*)&f0h[i];
    *(ushort4*)&wih0L[i+4]       = *(const ushort4*)&f0h[i+4];
    *(ushort4*)&wih0L[24576+i]   = *(const ushort4*)&f0l[i];
    *(ushort4*)&wih0L[24576+i+4] = *(const ushort4*)&f0l[i+4];
  }

  // resident HI fragments (144 VGPR), pinned
  short8 R0h[3][4], R1h[3][4], R2h[3][4];
  #pragma unroll
  for (int g = 0; g < 3; ++g)
    #pragma unroll
    for (int ks = 0; ks < 4; ++ks) {
      int fi = (w*3+g)*4 + ks;
      R0h[g][ks] = *(const short8*)&fr0h[fi*512 + lane*8];
      R1h[g][ks] = *(const short8*)&fr1h[fi*512 + lane*8];
      R2h[g][ks] = *(const short8*)&fr2h[fi*512 + lane*8];
      pinv(R0h[g][ks]); pinv(R1h[g][ks]); pinv(R2h[g][ks]);
    }

  const int nr = 16*w + ln;
  float brc0 = ldr1(bih0,nr,fb0)     + ldr1(bhh0,nr,fh0);
  float bzc0 = ldr1(bih0,nr+128,fb0) + ldr1(bhh0,nr+128,fh0);
  float bin0 = ldr1(bih0,nr+256,fb0);
  float bhn0 = ldr1(bhh0,nr+256,fh0);
  float brc1 = ldr1(bih1,nr,fb1)     + ldr1(bhh1,nr,fh1);
  float bzc1 = ldr1(bih1,nr+128,fb1) + ldr1(bhh1,nr+128,fh1);
  float bin1 = ldr1(bih1,nr+256,fb1);
  float bhn1 = ldr1(bhh1,nr+256,fh1);

  for (int i = tid; i < 2176; i += 512) {
    h0hi[i] = 0; h0lo[i] = 0; h1hi[i] = 0; h1lo[i] = 0;
  }
  float h0o[4] = {0.f,0.f,0.f,0.f};
  float h1o[4] = {0.f,0.f,0.f,0.f};
  __syncthreads();

  #pragma unroll 1
  for (int t = 0; t < TSTEPS; ++t) {
    // keep hi fragments live through the loop (no remat, no spill-to-mem path)
    #pragma unroll
    for (int g = 0; g < 3; ++g)
      #pragma unroll
      for (int ks = 0; ks < 4; ++ks) {
        pinv(R0h[g][ks]); pinv(R1h[g][ks]); pinv(R2h[g][ks]);
      }

    // stage x_t tile (16x64): 2 elems/thread, hi/lo split
    {
      int i0 = tid*2, m = i0 >> 6, f = i0 & 63;
      size_t base = ((size_t)(r0+m)*TSTEPS + t)*64 + f;
      float v0, v1;
      if (xf) { float2 xv = *(const float2*)((const float*)xg + base); v0 = xv.x; v1 = xv.y; }
      else { ushort2 u = *(const ushort2*)((const unsigned short*)xg + base); v0 = b2f(u.x); v1 = b2f(u.y); }
      unsigned short a0 = f2b(v0), a1 = f2b(v1);
      xhi[m*72+f] = a0;              xhi[m*72+f+1] = a1;
      xlo[m*72+f] = f2b(v0-b2f(a0)); xlo[m*72+f+1] = f2b(v1-b2f(a1));
    }

    // BATCH: layer-0 recurrent-lo fragments (12 loads in flight, latency
    // overlaps the x-stage barrier)
    short8 blv[12];
    #pragma unroll
    for (int ks = 0; ks < 4; ++ks)
      #pragma unroll
      for (int g = 0; g < 3; ++g)
        blv[ks*3+g] = *(const short8*)&fr0l[((w*3+g)*4+ks)*512 + lane*8];

    __syncthreads();

    // ---- layer 0 ----
    f32x4 acc[4];
    #pragma unroll
    for (int g = 0; g < 4; ++g) acc[g] = f4zero();
    #pragma unroll
    for (int ks = 0; ks < 2; ++ks) {          // x part (all LDS)
      short8 axh = *(const short8*)&xhi[ln*72 + ks*32 + kq*8];
      short8 axl = *(const short8*)&xlo[ln*72 + ks*32 + kq*8];
      #pragma unroll
      for (int g = 0; g < 3; ++g) {
        int fi = (w*3+g)*2 + ks;
        short8 bh = *(const short8*)&wih0L[fi*512 + lane*8];
        short8 bl = *(const short8*)&wih0L[24576 + fi*512 + lane*8];
        acc[g] = MFMA(axh, bh, acc[g], 0,0,0);
        acc[g] = MFMA(axh, bl, acc[g], 0,0,0);
        acc[g] = MFMA(axl, bh, acc[g], 0,0,0);
      }
    }
    #pragma unroll
    for (int ks = 0; ks < 4; ++ks) {          // h part: hi pinned, lo batched
      short8 ahh = *(const short8*)&h0hi[ln*136 + ks*32 + kq*8];
      short8 ahl = *(const short8*)&h0lo[ln*136 + ks*32 + kq*8];
      #pragma unroll
      for (int g = 0; g < 3; ++g) {
        int tgt = (g==2) ? 3 : g;
        acc[tgt] = MFMA(ahh, R0h[g][ks], acc[tgt], 0,0,0);
        acc[tgt] = MFMA(ahh, blv[ks*3+g], acc[tgt], 0,0,0);
        acc[tgt] = MFMA(ahl, R0h[g][ks], acc[tgt], 0,0,0);
      }
    }
    unsigned short nh[4], nl[4];
    #pragma unroll
    for (int rg = 0; rg < 4; ++rg) {
      float r  = sigm(acc[0][rg] + brc0);
      float z  = sigm(acc[1][rg] + bzc0);
      float nn = tanhfast(acc[2][rg] + bin0 + r*(acc[3][rg] + bhn0));
      float h  = nn + z*(h0o[rg] - nn);
      h0o[rg] = h;
      unsigned short hh = f2b(h);
      nh[rg] = hh; nl[rg] = f2b(h - b2f(hh));
    }
    __syncthreads();   // all h0 reads complete
    #pragma unroll
    for (int rg = 0; rg < 4; ++rg) {
      int off = (kq*4+rg)*136 + w*16 + ln;
      h0hi[off] = nh[rg]; h0lo[off] = nl[rg];
    }

    // BATCH: layer-1 input-lo (fr1l) — latency overlaps the h0-write barrier
    #pragma unroll
    for (int ks = 0; ks < 4; ++ks)
      #pragma unroll
      for (int g = 0; g < 3; ++g)
        blv[ks*3+g] = *(const short8*)&fr1l[((w*3+g)*4+ks)*512 + lane*8];

    __syncthreads();   // new h0 (= y0) ready

    // ---- layer 1, pass I: gi from y0 ----
    #pragma unroll
    for (int g = 0; g < 4; ++g) acc[g] = f4zero();
    #pragma unroll
    for (int ks = 0; ks < 4; ++ks) {
      short8 ayh = *(const short8*)&h0hi[ln*136 + ks*32 + kq*8];
      short8 ayl = *(const short8*)&h0lo[ln*136 + ks*32 + kq*8];
      #pragma unroll
      for (int g = 0; g < 3; ++g) {
        int tgtI = (g==2) ? 2 : g;
        acc[tgtI] = MFMA(ayh, R1h[g][ks], acc[tgtI], 0,0,0);
        acc[tgtI] = MFMA(ayh, blv[ks*3+g], acc[tgtI], 0,0,0);
        acc[tgtI] = MFMA(ayl, R1h[g][ks], acc[tgtI], 0,0,0);
      }
    }

    // BATCH: layer-1 recurrent-lo (fr2l)
    short8 bl2[12];
    #pragma unroll
    for (int ks = 0; ks < 4; ++ks)
      #pragma unroll
      for (int g = 0; g < 3; ++g)
        bl2[ks*3+g] = *(const short8*)&fr2l[((w*3+g)*4+ks)*512 + lane*8];

    // ---- layer 1, pass H: gh from h1 ----
    #pragma unroll
    for (int ks = 0; ks < 4; ++ks) {
      short8 a1h = *(const short8*)&h1hi[ln*136 + ks*32 + kq*8];
      short8 a1l = *(const short8*)&h1lo[ln*136 + ks*32 + kq*8];
      #pragma unroll
      for (int g = 0; g < 3; ++g) {
        int tgtH = (g==2) ? 3 : g;
        acc[tgtH] = MFMA(a1h, R2h[g][ks], acc[tgtH], 0,0,0);
        acc[tgtH] = MFMA(a1h, bl2[ks*3+g], acc[tgtH], 0,0,0);
        acc[tgtH] = MFMA(a1l, R2h[g][ks], acc[tgtH], 0,0,0);
      }
    }
    #pragma unroll
    for (int rg = 0; rg < 4; ++rg) {
      float r  = sigm(acc[0][rg] + brc1);
      float z  = sigm(acc[1][rg] + bzc1);
      float nn = tanhfast(acc[2][rg] + bin1 + r*(acc[3][rg] + bhn1));
      float h  = nn + z*(h1o[rg] - nn);
      h1o[rg] = h;
      unsigned short hh = f2b(h);
      nh[rg] = hh; nl[rg] = f2b(h - b2f(hh));
    }
    __syncthreads();   // all h1 reads complete
    #pragma unroll
    for (int rg = 0; rg < 4; ++rg) {
      int off = (kq*4+rg)*136 + w*16 + ln;
      h1hi[off] = nh[rg]; h1lo[off] = nl[rg];
    }
    // no trailing barrier: next h1 read is >= 2 barriers away
  }

  // epilogue: hid (fp32) + hid^T hi/lo (bf16)
  {
    int c = w*16 + ln;
    #pragma unroll
    for (int rg = 0; rg < 4; ++rg)
      hidg[(size_t)(r0 + kq*4 + rg)*HD + c] = h1o[rg];
    ushort4 ph, pl;
    unsigned short* hh = (unsigned short*)&ph;
    unsigned short* ll = (unsigned short*)&pl;
    #pragma unroll
    for (int rg = 0; rg < 4; ++rg) {
      hh[rg] = f2b(h1o[rg]);
      ll[rg] = f2b(h1o[rg] - b2f(hh[rg]));
    }
    size_t o = (size_t)c*NB + r0 + kq*4;
    *(ushort4*)&hTh[o] = ph;
    *(ushort4*)&hTl[o] = pl;
  }
}

// ---------------- s_j / s_i prep (fp32), 256 threads (validated R8) -------
template<bool WT32>
__device__ void sprep_body(
    const float* hidg, const void* wt, const void* bt, const void* a,
    int f_bt, int f_a, float* sjg, float* sig, float* hL, float* redb)
{
  const int tid = threadIdx.x;
  const int r0  = blockIdx.x * 16;
  for (int i = tid; i < 2048; i += 256) hL[i] = hidg[(size_t)r0*128 + i];
  __syncthreads();
  const int r = tid >> 4, cg = tid & 15, c0 = cg*8;
  float sjp = 0.f, sip = 0.f;
  #pragma unroll 1
  for (int cc = 0; cc < 8; ++cc) {
    int cI = c0 + cc;
    float acc = ldr1(bt, cI, f_bt);
    #pragma unroll 4
    for (int kq = 0; kq < 32; ++kq) {
      int k = kq*4;
      float4 wv = ldg4c<WT32>(wt, (size_t)cI*128 + k);
      float4 h = *(const float4*)&hL[r*128 + k];
      acc += wv.x*h.x + wv.y*h.y + wv.z*h.z + wv.w*h.w;
    }
    sjp += acc * ldr1(a, cI, f_a);
    sip += acc * ldr1(a, cI + 128, f_a);
  }
  redb[(r*16+cg)*2]   = sjp;
  redb[(r*16+cg)*2+1] = sip;
  __syncthreads();
  if (tid < 32) {
    int r2 = tid >> 1, wh = tid & 1;
    float s = 0.f;
    for (int g = 0; g < 16; ++g) s += redb[(r2*16+g)*2 + wh];
    if (wh == 0) sjg[r0+r2] = s; else sig[r0+r2] = s;
  }
}

__global__ __launch_bounds__(256) void sprep_kernel(
    const float* hidg, const void* wt, const void* bt, const void* a,
    float* sjg, float* sig)
{
  __shared__ float hL[2048];
  __shared__ float redb[512];
  __shared__ int sp;
  int f_wt = probe_f32(wt, 256, &sp);
  int f_bt = probe_f32(bt, 128, &sp);
  int f_a  = probe_f32(a,  256, &sp);
  if (f_wt) sprep_body<true >(hidg, wt, bt, a, f_bt, f_a, sjg, sig, hL, redb);
  else      sprep_body<false>(hidg, wt, bt, a, f_bt, f_a, sjg, sig, hL, redb);
}

// ---------------- MFMA attention + residual + MLP tail (validated R9) -----
template<bool PW32>
__device__ void attn_body(
    const float* sjg, const float* sig, const float* hidg,
    const unsigned short* hTh, const unsigned short* hTl,
    const void* wfc, const void* bfc, const void* wp1, const void* bp1,
    const void* wp2, const void* bp2,
    int f_bfc, int f_bp1, int f_wp2, float* outg,
    float* sjs, unsigned short* Pbuf, float* Obuf, float* redm,
    float* siL, float* miL, float* Zb)
{
  unsigned short* Phi = Pbuf;          // 16 x 520
  unsigned short* Plo = Pbuf + 8320;
  const int tid = threadIdx.x;
  const int w = tid >> 6, lane = tid & 63, ln = lane & 15, kq = lane >> 4;
  const int r0 = blockIdx.x * 16;

  for (int i = tid; i < 4096; i += 512) sjs[i] = sjg[i];
  __syncthreads();
  float mx = -1e30f;
  for (int i = tid; i < 4096; i += 512) mx = fmaxf(mx, sjs[i]);
  redm[tid] = mx;
  __syncthreads();
  for (int s = 256; s > 0; s >>= 1) {
    if (tid < s) redm[tid] = fmaxf(redm[tid], redm[tid+s]);
    __syncthreads();
  }
  if (tid < 16) {
    float si = sig[r0 + tid];
    siL[tid] = si;
    miL[tid] = lrelu(si + redm[0]);
  }
  __syncthreads();

  float zp[16];
  #pragma unroll
  for (int i = 0; i < 16; ++i) zp[i] = 0.f;
  f32x4 accO = f4zero();
  const int col = w*16 + ln;

  #pragma unroll 1
  for (int ch = 0; ch < 8; ++ch) {
    {
      float sjv = sjs[ch*512 + tid];
      #pragma unroll
      for (int i = 0; i < 16; ++i) {
        float v = lrelu(siL[i] + sjv);
        float p = __expf(v - miL[i]);
        zp[i] += p;
        unsigned short hh = f2b(p);
        Phi[i*520 + tid] = hh;
        Plo[i*520 + tid] = f2b(p - b2f(hh));
      }
    }
    __syncthreads();
    #pragma unroll
    for (int ks = 0; ks < 16; ++ks) {
      short8 Ah = *(const short8*)&Phi[ln*520 + ks*32 + kq*8];
      short8 Al = *(const short8*)&Plo[ln*520 + ks*32 + kq*8];
      size_t bo = (size_t)col*NB + ch*512 + ks*32 + kq*8;
      short8 Bh = *(const short8*)&hTh[bo];
      short8 Bl = *(const short8*)&hTl[bo];
      accO = MFMA(Ah, Bh, accO, 0,0,0);
      accO = MFMA(Ah, Bl, accO, 0,0,0);
      accO = MFMA(Al, Bh, accO, 0,0,0);
    }
    __syncthreads();
  }

  #pragma unroll
  for (int rg = 0; rg < 4; ++rg)
    Obuf[(kq*4+rg)*128 + col] = accO[rg];

  float* zarr = (float*)Pbuf;
  #pragma unroll
  for (int i = 0; i < 16; ++i) zarr[i*512 + tid] = zp[i];
  __syncthreads();
  {
    int row = tid >> 5, t0 = tid & 31;
    float s = 0.f;
    #pragma unroll
    for (int k = 0; k < 16; ++k) s += zarr[row*512 + t0 + 32*k];
    redm[row*32 + t0] = s;
  }
  __syncthreads();
  if (tid < 16) {
    float s = 0.f;
    for (int g = 0; g < 32; ++g) s += redm[tid*32 + g];
    Zb[tid] = s;
  }
  __syncthreads();

  {
    int e0 = tid*4, row = e0 >> 7, c = e0 & 127;
    float zi = Zb[row];
    #pragma unroll
    for (int e = 0; e < 4; ++e)
      Obuf[e0+e] = Obuf[e0+e]/zi + hidg[(size_t)(r0+row)*128 + c + e];
  }
  __syncthreads();

  float* h3f = sjs;
  {
    int o0 = tid*4, row = o0 >> 7, c = o0 & 127;
    #pragma unroll 1
    for (int e = 0; e < 4; ++e) {
      int cI = c + e;
      float acc = ldr1(bfc, cI, f_bfc);
      #pragma unroll 4
      for (int k4 = 0; k4 < 32; ++k4) {
        int k = k4*4;
        float4 wv = ldg4c<PW32>(wfc, (size_t)cI*128 + k);
        float4 h = *(const float4*)&Obuf[row*128 + k];
        acc += wv.x*h.x + wv.y*h.y + wv.z*h.z + wv.w*h.w;
      }
      h3f[row*128 + cI] = lrelu(acc);
    }
  }
  __syncthreads();

  float* h1f = (float*)Pbuf;
  {
    int o0 = tid*8, row = o0 >> 8, c = o0 & 255;
    #pragma unroll 1
    for (int e = 0; e < 8; ++e) {
      int cI = c + e;
      float acc = ldr1(bp1, cI, f_bp1);
      #pragma unroll 4
      for (int k4 = 0; k4 < 32; ++k4) {
        int k = k4*4;
        float4 wv = ldg4c<PW32>(wp1, (size_t)cI*128 + k);
        float4 h = *(const float4*)&h3f[row*128 + k];
        acc += wv.x*h.x + wv.y*h.y + wv.z*h.z + wv.w*h.w;
      }
      h1f[row*256 + cI] = 0.5f*acc*(1.0f + erff(acc*0.70710678118f));
    }
  }
  __syncthreads();

  {
    int row = tid >> 5, t0 = tid & 31;
    float s = 0.f;
    #pragma unroll
    for (int k = 0; k < 8; ++k) {
      int cI = t0 + 32*k;
      s += h1f[row*256 + cI] * ldr1(wp2, cI, f_wp2);
    }
    redm[row*32 + t0] = s;
  }
  __syncthreads();
  if (tid < 16) {
    float acc = ldr1(bp2, 0, f_bp1);
    for (int g = 0; g < 32; ++g) acc += redm[tid*32 + g];
    outg[r0 + tid] = acc;
  }
}

__global__ __launch_bounds__(512) void attn_kernel(
    const float* sjg, const float* sig, const float* hidg,
    const unsigned short* hTh, const unsigned short* hTl,
    const void* wfc, const void* bfc, const void* wp1, const void* bp1,
    const void* wp2, const void* bp2, float* outg)
{
  __shared__ float sjs[4096];
  __shared__ __align__(16) unsigned short Pbuf[16640];
  __shared__ float Obuf[2048];
  __shared__ float redm[512];
  __shared__ float siL[16], miL[16], Zb[16];
  __shared__ int sp;
  int f_wfc = probe_f32(wfc, 256, &sp);
  int f_bfc = probe_f32(bfc, 128, &sp);
  int f_bp1 = probe_f32(bp1, 256, &sp);
  int f_wp2 = probe_f32(wp2, 256, &sp);
  if (f_wfc) attn_body<true >(sjg, sig, hidg, hTh, hTl, wfc, bfc, wp1, bp1,
                              wp2, bp2, f_bfc, f_bp1, f_wp2, outg,
                              sjs, Pbuf, Obuf, redm, siL, miL, Zb);
  else       attn_body<false>(sjg, sig, hidg, hTh, hTl, wfc, bfc, wp1, bp1,
                              wp2, bp2, f_bfc, f_bp1, f_wp2, outg,
                              sjs, Pbuf, Obuf, redm, siL, miL, Zb);
}

extern "C" void kernel_launch(void* const* d_in, const int* in_sizes, int n_in,
                              void* d_out, int out_size, void* d_ws, size_t ws_size,
                              hipStream_t stream)
{
  float* out = (float*)d_out;
  const int expected[18] = {15728640,24576,49152,384,384,49152,49152,384,384,
                            16384,128,256,16384,128,32768,256,256,1};
  int bad = 0;
  if (n_in != 18 || out_size != 4096) bad = 1600;
  else for (int i = 0; i < 18; ++i) if (in_sizes[i] != expected[i]) { bad = 1600; break; }
  if (!bad && ws_size < (size_t)WS_NEED) bad = 1664;
  if (bad) { diag_kernel<<<16, 256, 0, stream>>>(out, (float)bad); return; }

  char* ws = (char*)d_ws;
  float*          sj  = (float*)(ws + WS_SJ);
  float*          si  = (float*)(ws + WS_SI);
  float*          hid = (float*)(ws + WS_HID);
  unsigned short* hTh = (unsigned short*)(ws + WS_HTH);
  unsigned short* hTl = (unsigned short*)(ws + WS_HTL);

  repack_kernel<<<256, 256, 0, stream>>>(d_in[1], d_in[2], d_in[5], d_in[6], ws);
  gru_kernel<<<256, 512, 0, stream>>>(d_in[0], d_in[3], d_in[4], d_in[7], d_in[8],
                                      ws, hid, hTh, hTl);
  sprep_kernel<<<256, 256, 0, stream>>>(hid, d_in[9], d_in[10], d_in[11], sj, si);
  attn_kernel<<<256, 512, 0, stream>>>(sj, si, hid, hTh, hTl,
                                       d_in[12], d_in[13], d_in[14], d_in[15],
                                       d_in[16], d_in[17], out);
}

// Round 12
// 614.232 us; speedup vs baseline: 2.0339x; 2.0339x over previous
//
#include <hip/hip_runtime.h>
#include <cstdint>
#include <cstddef>

#define TSTEPS 60
#define NB 4096
#define HD 128

typedef __attribute__((ext_vector_type(8))) short short8;
typedef __attribute__((ext_vector_type(4))) float f32x4;

// ---------------- workspace layout (byte offsets) ----------------
#define WS_SJ    0
#define WS_SI    16384
#define WS_HID   32768                 // 4096*128 f32 = 2 MB
#define WS_HTH   2129920               // hid^T hi bf16 [128][4096] = 1 MB
#define WS_HTL   3178496               // hid^T lo bf16 = 1 MB
#define WS_F0H   4227072               // wih0 hi frags 49152 B
#define WS_F0L   (WS_F0H+49152)
#define WS_FR0H  (WS_F0L+49152)        // whh0 hi 98304 B
#define WS_FR0L  (WS_FR0H+98304)
#define WS_FR1H  (WS_FR0L+98304)
#define WS_FR1L  (WS_FR1H+98304)
#define WS_FR2H  (WS_FR1L+98304)
#define WS_FR2L  (WS_FR2H+98304)
#define WS_BASE  (WS_FR2L+98304)
#define WS_Y0P   WS_BASE               // packed y0 (hi|lo) uint: 256*60*2048*4
#define WS_FULL  (WS_Y0P + 125829120ULL)

__device__ __forceinline__ float b2f(unsigned short h){ return __uint_as_float(((unsigned)h)<<16); }
__device__ __forceinline__ unsigned short f2b(float f){
  unsigned u = __float_as_uint(f);
  u = (u + 0x7FFFu + ((u>>16)&1u)) >> 16;
  return (unsigned short)u;
}
__device__ __forceinline__ float sigm(float x){ return 1.0f/(1.0f + __expf(-x)); }
__device__ __forceinline__ float tanhfast(float x){
  float xc = fminf(fmaxf(x,-15.0f),15.0f);
  float e = __expf(2.0f*xc);
  return (e-1.0f)/(e+1.0f);
}
__device__ __forceinline__ float lrelu(float x){ return x > 0.0f ? x : 0.01f*x; }
__device__ __forceinline__ float ldr1(const void* p, size_t i, int f32){
  return f32 ? ((const float*)p)[i] : b2f(((const unsigned short*)p)[i]);
}
template<bool F32>
__device__ __forceinline__ float4 ldg4c(const void* p, size_t i){
  if (F32) return *(const float4*)((const float*)p + i);
  ushort4 u = *(const ushort4*)((const unsigned short*)p + i);
  float4 f; f.x=b2f(u.x); f.y=b2f(u.y); f.z=b2f(u.z); f.w=b2f(u.w); return f;
}
__device__ __forceinline__ f32x4 f4zero(){ f32x4 v = {0.f,0.f,0.f,0.f}; return v; }
__device__ __forceinline__ void pinv(short8& v){ asm volatile("" : "+v"(v)); }

// Block-uniform dtype probe (validated R7/R8): 1 = fp32, 0 = bf16.
__device__ int probe_f32(const void* p, int nprobe, volatile int* s){
  if (threadIdx.x == 0) *s = 0;
  __syncthreads();
  if ((int)threadIdx.x < nprobe) {
    float v = b2f(((const unsigned short*)p)[threadIdx.x]);
    if (!(v == v) || fabsf(v) > 1e4f) *s = 1;
  }
  __syncthreads();
  int r = *s;
  __syncthreads();
  return r;
}

__global__ void diag_kernel(float* out, float code){
  int i = blockIdx.x*256 + threadIdx.x;
  if (i < 4096) out[i] = code;
}

// ---------------- weight repack (validated R8) ----------------------------
__device__ void repack_mat(const void* src, int f32, int K, int nks,
                           unsigned short* hi, unsigned short* lo,
                           int tid, int nthr){
  int total = 384*K;
  for (int idx = tid; idx < total; idx += nthr) {
    int j = idx & 7, lane = (idx>>3)&63, t = idx>>9;
    int ks = t % nks, g = (t/nks)%3, w = t/(nks*3);
    int row = 16*(w + 8*g) + (lane & 15);
    int k   = ks*32 + ((lane>>4)<<3) + j;
    float v = f32 ? ((const float*)src)[(size_t)row*K + k]
                  : b2f(((const unsigned short*)src)[(size_t)row*K + k]);
    unsigned short h = f2b(v);
    hi[idx] = h;
    lo[idx] = f2b(v - b2f(h));
  }
}

__global__ __launch_bounds__(256) void repack_kernel(
    const void* wih0, const void* whh0, const void* wih1, const void* whh1,
    char* ws)
{
  __shared__ int sp;
  int f0 = probe_f32(wih0, 256, &sp);
  int f1 = probe_f32(whh0, 256, &sp);
  int f2 = probe_f32(wih1, 256, &sp);
  int f3 = probe_f32(whh1, 256, &sp);
  int tid  = blockIdx.x*256 + threadIdx.x;
  int nthr = gridDim.x*256;
  repack_mat(wih0, f0,  64, 2, (unsigned short*)(ws+WS_F0H),  (unsigned short*)(ws+WS_F0L),  tid, nthr);
  repack_mat(whh0, f1, 128, 4, (unsigned short*)(ws+WS_FR0H), (unsigned short*)(ws+WS_FR0L), tid, nthr);
  repack_mat(wih1, f2, 128, 4, (unsigned short*)(ws+WS_FR1H), (unsigned short*)(ws+WS_FR1L), tid, nthr);
  repack_mat(whh1, f3, 128, 4, (unsigned short*)(ws+WS_FR2H), (unsigned short*)(ws+WS_FR2L), tid, nthr);
}

#define MFMA __builtin_amdgcn_mfma_f32_16x16x32_bf16

// ---------------- PHASE 0: layer-0 GRU, all 60 steps, 16 rows/block -------
// wih0 hi+lo in LDS (96 KB); whh0 hi+lo PINNED (96 VGPR). x prefetched,
// double-buffered. y0 written to global packed (hi | lo<<16) per element.
__global__ __launch_bounds__(512) __attribute__((amdgpu_waves_per_eu(2,2)))
void gru0_kernel(const void* __restrict__ xg,
                 const void* __restrict__ bih0, const void* __restrict__ bhh0,
                 const char* __restrict__ ws, unsigned* __restrict__ y0p)
{
  __shared__ __align__(16) unsigned short wih0L[49152];          // hi | lo
  __shared__ __align__(16) unsigned short xbh[2][1152], xbl[2][1152];
  __shared__ __align__(16) unsigned short h0hi[2176], h0lo[2176];
  __shared__ int sp;
  const int tid  = threadIdx.x;
  const int w    = tid >> 6;
  const int lane = tid & 63;
  const int ln   = lane & 15;
  const int kq   = lane >> 4;
  const int r0   = blockIdx.x * 16;

  int xf  = probe_f32(xg,   256, &sp);
  int fb0 = probe_f32(bih0, 256, &sp);
  int fh0 = probe_f32(bhh0, 256, &sp);

  const unsigned short* f0h  = (const unsigned short*)(ws+WS_F0H);
  const unsigned short* f0l  = (const unsigned short*)(ws+WS_F0L);
  const unsigned short* fr0h = (const unsigned short*)(ws+WS_FR0H);
  const unsigned short* fr0l = (const unsigned short*)(ws+WS_FR0L);

  for (int i = tid*8; i < 24576; i += 4096) {
    *(ushort4*)&wih0L[i]         = *(const ushort4*)&f0h[i];
    *(ushort4*)&wih0L[i+4]       = *(const ushort4*)&f0h[i+4];
    *(ushort4*)&wih0L[24576+i]   = *(const ushort4*)&f0l[i];
    *(ushort4*)&wih0L[24576+i+4] = *(const ushort4*)&f0l[i+4];
  }

  short8 R0h[3][4], R0l[3][4];
  #pragma unroll
  for (int g = 0; g < 3; ++g)
    #pragma unroll
    for (int ks = 0; ks < 4; ++ks) {
      int fi = (w*3+g)*4 + ks;
      R0h[g][ks] = *(const short8*)&fr0h[fi*512 + lane*8];
      R0l[g][ks] = *(const short8*)&fr0l[fi*512 + lane*8];
      pinv(R0h[g][ks]); pinv(R0l[g][ks]);
    }

  const int nr = 16*w + ln;
  float brc0 = ldr1(bih0,nr,fb0)     + ldr1(bhh0,nr,fh0);
  float bzc0 = ldr1(bih0,nr+128,fb0) + ldr1(bhh0,nr+128,fh0);
  float bin0 = ldr1(bih0,nr+256,fb0);
  float bhn0 = ldr1(bhh0,nr+256,fh0);

  for (int i = tid; i < 2176; i += 512) { h0hi[i] = 0; h0lo[i] = 0; }
  // stage x(0) into buffer 0
  const int xm = tid >> 5, xfc = (tid & 31)*2;   // 16 rows x 64 (2/thread)
  {
    size_t base = ((size_t)(r0+xm)*TSTEPS + 0)*64 + xfc;
    float v0, v1;
    if (xf) { float2 xv = *(const float2*)((const float*)xg + base); v0 = xv.x; v1 = xv.y; }
    else { ushort2 u = *(const ushort2*)((const unsigned short*)xg + base); v0 = b2f(u.x); v1 = b2f(u.y); }
    unsigned short a0 = f2b(v0), a1 = f2b(v1);
    xbh[0][xm*72+xfc] = a0;              xbh[0][xm*72+xfc+1] = a1;
    xbl[0][xm*72+xfc] = f2b(v0-b2f(a0)); xbl[0][xm*72+xfc+1] = f2b(v1-b2f(a1));
  }
  float h0o[4] = {0.f,0.f,0.f,0.f};
  __syncthreads();

  #pragma unroll 1
  for (int t = 0; t < TSTEPS; ++t) {
    const int b0 = t & 1, b1 = b0 ^ 1;
    // prefetch x(t+1) into registers
    unsigned short pa0=0, pa1=0, pl0=0, pl1=0;
    if (t+1 < TSTEPS) {
      size_t base = ((size_t)(r0+xm)*TSTEPS + (t+1))*64 + xfc;
      float v0, v1;
      if (xf) { float2 xv = *(const float2*)((const float*)xg + base); v0 = xv.x; v1 = xv.y; }
      else { ushort2 u = *(const ushort2*)((const unsigned short*)xg + base); v0 = b2f(u.x); v1 = b2f(u.y); }
      pa0 = f2b(v0); pa1 = f2b(v1);
      pl0 = f2b(v0-b2f(pa0)); pl1 = f2b(v1-b2f(pa1));
    }

    f32x4 acc[4];
    #pragma unroll
    for (int g = 0; g < 4; ++g) acc[g] = f4zero();
    #pragma unroll
    for (int ks = 0; ks < 2; ++ks) {          // x part (LDS weights)
      short8 axh = *(const short8*)&xbh[b0][ln*72 + ks*32 + kq*8];
      short8 axl = *(const short8*)&xbl[b0][ln*72 + ks*32 + kq*8];
      #pragma unroll
      for (int g = 0; g < 3; ++g) {
        int fi = (w*3+g)*2 + ks;
        short8 bh = *(const short8*)&wih0L[fi*512 + lane*8];
        short8 bl = *(const short8*)&wih0L[24576 + fi*512 + lane*8];
        acc[g] = MFMA(axh, bh, acc[g], 0,0,0);
        acc[g] = MFMA(axh, bl, acc[g], 0,0,0);
        acc[g] = MFMA(axl, bh, acc[g], 0,0,0);
      }
    }
    #pragma unroll
    for (int ks = 0; ks < 4; ++ks) {          // h part (pinned weights)
      short8 ahh = *(const short8*)&h0hi[ln*136 + ks*32 + kq*8];
      short8 ahl = *(const short8*)&h0lo[ln*136 + ks*32 + kq*8];
      #pragma unroll
      for (int g = 0; g < 3; ++g) {
        int tgt = (g==2) ? 3 : g;
        acc[tgt] = MFMA(ahh, R0h[g][ks], acc[tgt], 0,0,0);
        acc[tgt] = MFMA(ahh, R0l[g][ks], acc[tgt], 0,0,0);
        acc[tgt] = MFMA(ahl, R0h[g][ks], acc[tgt], 0,0,0);
      }
    }
    unsigned short nh[4], nl[4];
    #pragma unroll
    for (int rg = 0; rg < 4; ++rg) {
      float r  = sigm(acc[0][rg] + brc0);
      float z  = sigm(acc[1][rg] + bzc0);
      float nn = tanhfast(acc[2][rg] + bin0 + r*(acc[3][rg] + bhn0));
      float h  = nn + z*(h0o[rg] - nn);
      h0o[rg] = h;
      unsigned short hh = f2b(h);
      nh[rg] = hh; nl[rg] = f2b(h - b2f(hh));
    }
    // y0 write (registers, packed); 64-B contiguous per (wave,kq,rg)
    {
      size_t ybase = ((size_t)blockIdx.x*TSTEPS + t)*2048;
      #pragma unroll
      for (int rg = 0; rg < 4; ++rg)
        y0p[ybase + (kq*4+rg)*128 + w*16 + ln] =
            (unsigned)nh[rg] | ((unsigned)nl[rg] << 16);
    }
    // stage prefetched x into the other buffer
    if (t+1 < TSTEPS) {
      xbh[b1][xm*72+xfc] = pa0; xbh[b1][xm*72+xfc+1] = pa1;
      xbl[b1][xm*72+xfc] = pl0; xbl[b1][xm*72+xfc+1] = pl1;
    }
    __syncthreads();   // all h0-tile reads complete (+ x writes ordered)
    #pragma unroll
    for (int rg = 0; rg < 4; ++rg) {
      int off = (kq*4+rg)*136 + w*16 + ln;
      h0hi[off] = nh[rg]; h0lo[off] = nl[rg];
    }
    __syncthreads();   // h0 ready for t+1
  }
}

// ---------------- PHASE 1: layer-1 GRU, all 60 steps, 16 rows/block -------
// wih1-hi in LDS (96 KB); wih1-lo + whh1 hi+lo PINNED (144 VGPR). y0
// prefetched from global (packed), double-buffered in LDS.
__global__ __launch_bounds__(512) __attribute__((amdgpu_waves_per_eu(2,2)))
void gru1_kernel(const void* __restrict__ bih1, const void* __restrict__ bhh1,
                 const char* __restrict__ ws, const unsigned* __restrict__ y0p,
                 float* __restrict__ hidg,
                 unsigned short* __restrict__ hTh, unsigned short* __restrict__ hTl)
{
  __shared__ __align__(16) unsigned short wih1hL[49152];         // hi only
  __shared__ __align__(16) unsigned short ybh[2][2176], ybl[2][2176];
  __shared__ __align__(16) unsigned short h1hi[2176], h1lo[2176];
  __shared__ int sp;
  const int tid  = threadIdx.x;
  const int w    = tid >> 6;
  const int lane = tid & 63;
  const int ln   = lane & 15;
  const int kq   = lane >> 4;
  const int r0   = blockIdx.x * 16;

  int fb1 = probe_f32(bih1, 256, &sp);
  int fh1 = probe_f32(bhh1, 256, &sp);

  const unsigned short* fr1h = (const unsigned short*)(ws+WS_FR1H);
  const unsigned short* fr1l = (const unsigned short*)(ws+WS_FR1L);
  const unsigned short* fr2h = (const unsigned short*)(ws+WS_FR2H);
  const unsigned short* fr2l = (const unsigned short*)(ws+WS_FR2L);

  for (int i = tid*8; i < 49152; i += 4096) {
    *(ushort4*)&wih1hL[i]   = *(const ushort4*)&fr1h[i];
    *(ushort4*)&wih1hL[i+4] = *(const ushort4*)&fr1h[i+4];
  }

  short8 W1l[3][4], R2h[3][4], R2l[3][4];
  #pragma unroll
  for (int g = 0; g < 3; ++g)
    #pragma unroll
    for (int ks = 0; ks < 4; ++ks) {
      int fi = (w*3+g)*4 + ks;
      W1l[g][ks] = *(const short8*)&fr1l[fi*512 + lane*8];
      R2h[g][ks] = *(const short8*)&fr2h[fi*512 + lane*8];
      R2l[g][ks] = *(const short8*)&fr2l[fi*512 + lane*8];
      pinv(W1l[g][ks]); pinv(R2h[g][ks]); pinv(R2l[g][ks]);
    }

  const int nr = 16*w + ln;
  float brc1 = ldr1(bih1,nr,fb1)     + ldr1(bhh1,nr,fh1);
  float bzc1 = ldr1(bih1,nr+128,fb1) + ldr1(bhh1,nr+128,fh1);
  float bin1 = ldr1(bih1,nr+256,fb1);
  float bhn1 = ldr1(bhh1,nr+256,fh1);

  for (int i = tid; i < 2176; i += 512) { h1hi[i] = 0; h1lo[i] = 0; }
  // stage y(0) into buffer 0
  const int yi4 = tid*4, yrow = yi4 >> 7, ycol = yi4 & 127;
  {
    uint4 pv = *(const uint4*)&y0p[((size_t)blockIdx.x*TSTEPS + 0)*2048 + yi4];
    ushort4 vh, vl;
    vh.x=(unsigned short)(pv.x&0xffff); vl.x=(unsigned short)(pv.x>>16);
    vh.y=(unsigned short)(pv.y&0xffff); vl.y=(unsigned short)(pv.y>>16);
    vh.z=(unsigned short)(pv.z&0xffff); vl.z=(unsigned short)(pv.z>>16);
    vh.w=(unsigned short)(pv.w&0xffff); vl.w=(unsigned short)(pv.w>>16);
    *(ushort4*)&ybh[0][yrow*136+ycol] = vh;
    *(ushort4*)&ybl[0][yrow*136+ycol] = vl;
  }
  float h1o[4] = {0.f,0.f,0.f,0.f};
  __syncthreads();

  #pragma unroll 1
  for (int t = 0; t < TSTEPS; ++t) {
    const int b0 = t & 1, b1 = b0 ^ 1;
    uint4 pv = {0,0,0,0};
    if (t+1 < TSTEPS)
      pv = *(const uint4*)&y0p[((size_t)blockIdx.x*TSTEPS + (t+1))*2048 + yi4];

    f32x4 acc[4];
    #pragma unroll
    for (int g = 0; g < 4; ++g) acc[g] = f4zero();
    #pragma unroll
    for (int ks = 0; ks < 4; ++ks) {
      short8 ayh = *(const short8*)&ybh[b0][ln*136 + ks*32 + kq*8];
      short8 ayl = *(const short8*)&ybl[b0][ln*136 + ks*32 + kq*8];
      short8 a1h = *(const short8*)&h1hi[ln*136 + ks*32 + kq*8];
      short8 a1l = *(const short8*)&h1lo[ln*136 + ks*32 + kq*8];
      #pragma unroll
      for (int g = 0; g < 3; ++g) {
        int tgtI = (g==2) ? 2 : g;
        int tgtH = (g==2) ? 3 : g;
        short8 bh = *(const short8*)&wih1hL[((w*3+g)*4+ks)*512 + lane*8];
        acc[tgtI] = MFMA(ayh, bh,         acc[tgtI], 0,0,0);
        acc[tgtI] = MFMA(ayh, W1l[g][ks], acc[tgtI], 0,0,0);
        acc[tgtI] = MFMA(ayl, bh,         acc[tgtI], 0,0,0);
        acc[tgtH] = MFMA(a1h, R2h[g][ks], acc[tgtH], 0,0,0);
        acc[tgtH] = MFMA(a1h, R2l[g][ks], acc[tgtH], 0,0,0);
        acc[tgtH] = MFMA(a1l, R2h[g][ks], acc[tgtH], 0,0,0);
      }
    }
    unsigned short nh[4], nl[4];
    #pragma unroll
    for (int rg = 0; rg < 4; ++rg) {
      float r  = sigm(acc[0][rg] + brc1);
      float z  = sigm(acc[1][rg] + bzc1);
      float nn = tanhfast(acc[2][rg] + bin1 + r*(acc[3][rg] + bhn1));
      float h  = nn + z*(h1o[rg] - nn);
      h1o[rg] = h;
      unsigned short hh = f2b(h);
      nh[rg] = hh; nl[rg] = f2b(h - b2f(hh));
    }
    if (t+1 < TSTEPS) {
      ushort4 vh, vl;
      vh.x=(unsigned short)(pv.x&0xffff); vl.x=(unsigned short)(pv.x>>16);
      vh.y=(unsigned short)(pv.y&0xffff); vl.y=(unsigned short)(pv.y>>16);
      vh.z=(unsigned short)(pv.z&0xffff); vl.z=(unsigned short)(pv.z>>16);
      vh.w=(unsigned short)(pv.w&0xffff); vl.w=(unsigned short)(pv.w>>16);
      *(ushort4*)&ybh[b1][yrow*136+ycol] = vh;
      *(ushort4*)&ybl[b1][yrow*136+ycol] = vl;
    }
    __syncthreads();   // all h1-tile reads complete (+ y writes ordered)
    #pragma unroll
    for (int rg = 0; rg < 4; ++rg) {
      int off = (kq*4+rg)*136 + w*16 + ln;
      h1hi[off] = nh[rg]; h1lo[off] = nl[rg];
    }
    __syncthreads();   // h1 ready for t+1
  }

  // epilogue: hid (fp32) + hid^T hi/lo (bf16)
  {
    int c = w*16 + ln;
    #pragma unroll
    for (int rg = 0; rg < 4; ++rg)
      hidg[(size_t)(r0 + kq*4 + rg)*HD + c] = h1o[rg];
    ushort4 ph, pl;
    unsigned short* hh = (unsigned short*)&ph;
    unsigned short* ll = (unsigned short*)&pl;
    #pragma unroll
    for (int rg = 0; rg < 4; ++rg) {
      hh[rg] = f2b(h1o[rg]);
      ll[rg] = f2b(h1o[rg] - b2f(hh[rg]));
    }
    size_t o = (size_t)c*NB + r0 + kq*4;
    *(ushort4*)&hTh[o] = ph;
    *(ushort4*)&hTl[o] = pl;
  }
}

// ---------------- FALLBACK: R10 fused GRU (780 µs, proven) ----------------
__global__ __launch_bounds__(512, 1) void gru_fb_kernel(
    const void* __restrict__ xg,
    const void* __restrict__ bih0, const void* __restrict__ bhh0,
    const void* __restrict__ bih1, const void* __restrict__ bhh1,
    const char* __restrict__ ws, float* __restrict__ hidg,
    unsigned short* __restrict__ hTh, unsigned short* __restrict__ hTl)
{
  __shared__ __align__(16) unsigned short wih0L[49152];
  __shared__ __align__(16) unsigned short xhi[1152], xlo[1152];
  __shared__ __align__(16) unsigned short h0hi[2176], h0lo[2176];
  __shared__ __align__(16) unsigned short h1hi[2176], h1lo[2176];
  __shared__ int sp;
  const int tid  = threadIdx.x;
  const int w    = tid >> 6;
  const int lane = tid & 63;
  const int ln   = lane & 15;
  const int kq   = lane >> 4;
  const int r0   = blockIdx.x * 16;

  int xf  = probe_f32(xg,   256, &sp);
  int fb0 = probe_f32(bih0, 256, &sp);
  int fh0 = probe_f32(bhh0, 256, &sp);
  int fb1 = probe_f32(bih1, 256, &sp);
  int fh1 = probe_f32(bhh1, 256, &sp);

  const unsigned short* f0h  = (const unsigned short*)(ws+WS_F0H);
  const unsigned short* f0l  = (const unsigned short*)(ws+WS_F0L);
  const unsigned short* fr0h = (const unsigned short*)(ws+WS_FR0H);
  const unsigned short* fr0l = (const unsigned short*)(ws+WS_FR0L);
  const unsigned short* fr1h = (const unsigned short*)(ws+WS_FR1H);
  const unsigned short* fr1l = (const unsigned short*)(ws+WS_FR1L);
  const unsigned short* fr2h = (const unsigned short*)(ws+WS_FR2H);
  const unsigned short* fr2l = (const unsigned short*)(ws+WS_FR2L);

  for (int i = tid*8; i < 24576; i += 4096) {
    *(ushort4*)&wih0L[i]         = *(const ushort4*)&f0h[i];
    *(ushort4*)&wih0L[i+4]       = *(const ushort4*)&f0h[i+4];
    *(ushort4*)&wih0L[24576+i]   = *(const ushort4*)&f0l[i];
    *(ushort4*)&wih0L[24576+i+4] = *(const ushort4*)&f0l[i+4];
  }
  short8 R0h[3][4], R1h[3][4], R2h[3][4];
  #pragma unroll
  for (int g = 0; g < 3; ++g)
    #pragma unroll
    for (int ks = 0; ks < 4; ++ks) {
      int fi = (w*3+g)*4 + ks;
      R0h[g][ks] = *(const short8*)&fr0h[fi*512 + lane*8];
      R1h[g][ks] = *(const short8*)&fr1h[fi*512 + lane*8];
      R2h[g][ks] = *(const short8*)&fr2h[fi*512 + lane*8];
      pinv(R0h[g][ks]); pinv(R1h[g][ks]); pinv(R2h[g][ks]);
    }
  const int nr = 16*w + ln;
  float brc0 = ldr1(bih0,nr,fb0)     + ldr1(bhh0,nr,fh0);
  float bzc0 = ldr1(bih0,nr+128,fb0) + ldr1(bhh0,nr+128,fh0);
  float bin0 = ldr1(bih0,nr+256,fb0);
  float bhn0 = ldr1(bhh0,nr+256,fh0);
  float brc1 = ldr1(bih1,nr,fb1)     + ldr1(bhh1,nr,fh1);
  float bzc1 = ldr1(bih1,nr+128,fb1) + ldr1(bhh1,nr+128,fh1);
  float bin1 = ldr1(bih1,nr+256,fb1);
  float bhn1 = ldr1(bhh1,nr+256,fh1);

  for (int i = tid; i < 2176; i += 512) {
    h0hi[i] = 0; h0lo[i] = 0; h1hi[i] = 0; h1lo[i] = 0;
  }
  float h0o[4] = {0.f,0.f,0.f,0.f};
  float h1o[4] = {0.f,0.f,0.f,0.f};
  __syncthreads();

  #pragma unroll 1
  for (int t = 0; t < TSTEPS; ++t) {
    {
      int i0 = tid*2, m = i0 >> 6, f = i0 & 63;
      size_t base = ((size_t)(r0+m)*TSTEPS + t)*64 + f;
      float v0, v1;
      if (xf) { float2 xv = *(const float2*)((const float*)xg + base); v0 = xv.x; v1 = xv.y; }
      else { ushort2 u = *(const ushort2*)((const unsigned short*)xg + base); v0 = b2f(u.x); v1 = b2f(u.y); }
      unsigned short a0 = f2b(v0), a1 = f2b(v1);
      xhi[m*72+f] = a0;              xhi[m*72+f+1] = a1;
      xlo[m*72+f] = f2b(v0-b2f(a0)); xlo[m*72+f+1] = f2b(v1-b2f(a1));
    }
    __syncthreads();
    f32x4 acc[4];
    #pragma unroll
    for (int g = 0; g < 4; ++g) acc[g] = f4zero();
    #pragma unroll
    for (int ks = 0; ks < 2; ++ks) {
      short8 axh = *(const short8*)&xhi[ln*72 + ks*32 + kq*8];
      short8 axl = *(const short8*)&xlo[ln*72 + ks*32 + kq*8];
      #pragma unroll
      for (int g = 0; g < 3; ++g) {
        int fi = (w*3+g)*2 + ks;
        short8 bh = *(const short8*)&wih0L[fi*512 + lane*8];
        short8 bl = *(const short8*)&wih0L[24576 + fi*512 + lane*8];
        acc[g] = MFMA(axh, bh, acc[g], 0,0,0);
        acc[g] = MFMA(axh, bl, acc[g], 0,0,0);
        acc[g] = MFMA(axl, bh, acc[g], 0,0,0);
      }
    }
    #pragma unroll
    for (int ks = 0; ks < 4; ++ks) {
      short8 ahh = *(const short8*)&h0hi[ln*136 + ks*32 + kq*8];
      short8 ahl = *(const short8*)&h0lo[ln*136 + ks*32 + kq*8];
      #pragma unroll
      for (int g = 0; g < 3; ++g) {
        int tgt = (g==2) ? 3 : g;
        short8 bl = *(const short8*)&fr0l[((w*3+g)*4+ks)*512 + lane*8];
        acc[tgt] = MFMA(ahh, R0h[g][ks], acc[tgt], 0,0,0);
        acc[tgt] = MFMA(ahh, bl,         acc[tgt], 0,0,0);
        acc[tgt] = MFMA(ahl, R0h[g][ks], acc[tgt], 0,0,0);
      }
    }
    unsigned short nh[4], nl[4];
    #pragma unroll
    for (int rg = 0; rg < 4; ++rg) {
      float r  = sigm(acc[0][rg] + brc0);
      float z  = sigm(acc[1][rg] + bzc0);
      float nn = tanhfast(acc[2][rg] + bin0 + r*(acc[3][rg] + bhn0));
      float h  = nn + z*(h0o[rg] - nn);
      h0o[rg] = h;
      unsigned short hh = f2b(h);
      nh[rg] = hh; nl[rg] = f2b(h - b2f(hh));
    }
    __syncthreads();
    #pragma unroll
    for (int rg = 0; rg < 4; ++rg) {
      int off = (kq*4+rg)*136 + w*16 + ln;
      h0hi[off] = nh[rg]; h0lo[off] = nl[rg];
    }
    __syncthreads();
    #pragma unroll
    for (int g = 0; g < 4; ++g) acc[g] = f4zero();
    #pragma unroll
    for (int ks = 0; ks < 4; ++ks) {
      short8 ayh = *(const short8*)&h0hi[ln*136 + ks*32 + kq*8];
      short8 ayl = *(const short8*)&h0lo[ln*136 + ks*32 + kq*8];
      short8 a1h = *(const short8*)&h1hi[ln*136 + ks*32 + kq*8];
      short8 a1l = *(const short8*)&h1lo[ln*136 + ks*32 + kq*8];
      #pragma unroll
      for (int g = 0; g < 3; ++g) {
        int tgtI = (g==2) ? 2 : g;
        int tgtH = (g==2) ? 3 : g;
        short8 blI = *(const short8*)&fr1l[((w*3+g)*4+ks)*512 + lane*8];
        short8 blH = *(const short8*)&fr2l[((w*3+g)*4+ks)*512 + lane*8];
        acc[tgtI] = MFMA(ayh, R1h[g][ks], acc[tgtI], 0,0,0);
        acc[tgtI] = MFMA(ayh, blI,        acc[tgtI], 0,0,0);
        acc[tgtI] = MFMA(ayl, R1h[g][ks], acc[tgtI], 0,0,0);
        acc[tgtH] = MFMA(a1h, R2h[g][ks], acc[tgtH], 0,0,0);
        acc[tgtH] = MFMA(a1h, blH,        acc[tgtH], 0,0,0);
        acc[tgtH] = MFMA(a1l, R2h[g][ks], acc[tgtH], 0,0,0);
      }
    }
    #pragma unroll
    for (int rg = 0; rg < 4; ++rg) {
      float r  = sigm(acc[0][rg] + brc1);
      float z  = sigm(acc[1][rg] + bzc1);
      float nn = tanhfast(acc[2][rg] + bin1 + r*(acc[3][rg] + bhn1));
      float h  = nn + z*(h1o[rg] - nn);
      h1o[rg] = h;
      unsigned short hh = f2b(h);
      nh[rg] = hh; nl[rg] = f2b(h - b2f(hh));
    }
    __syncthreads();
    #pragma unroll
    for (int rg = 0; rg < 4; ++rg) {
      int off = (kq*4+rg)*136 + w*16 + ln;
      h1hi[off] = nh[rg]; h1lo[off] = nl[rg];
    }
  }
  {
    int c = w*16 + ln;
    #pragma unroll
    for (int rg = 0; rg < 4; ++rg)
      hidg[(size_t)(r0 + kq*4 + rg)*HD + c] = h1o[rg];
    ushort4 ph, pl;
    unsigned short* hh = (unsigned short*)&ph;
    unsigned short* ll = (unsigned short*)&pl;
    #pragma unroll
    for (int rg = 0; rg < 4; ++rg) {
      hh[rg] = f2b(h1o[rg]);
      ll[rg] = f2b(h1o[rg] - b2f(hh[rg]));
    }
    size_t o = (size_t)c*NB + r0 + kq*4;
    *(ushort4*)&hTh[o] = ph;
    *(ushort4*)&hTl[o] = pl;
  }
}

// ---------------- s_j / s_i prep (fp32), 256 threads (validated R8) -------
template<bool WT32>
__device__ void sprep_body(
    const float* hidg, const void* wt, const void* bt, const void* a,
    int f_bt, int f_a, float* sjg, float* sig, float* hL, float* redb)
{
  const int tid = threadIdx.x;
  const int r0  = blockIdx.x * 16;
  for (int i = tid; i < 2048; i += 256) hL[i] = hidg[(size_t)r0*128 + i];
  __syncthreads();
  const int r = tid >> 4, cg = tid & 15, c0 = cg*8;
  float sjp = 0.f, sip = 0.f;
  #pragma unroll 1
  for (int cc = 0; cc < 8; ++cc) {
    int cI = c0 + cc;
    float acc = ldr1(bt, cI, f_bt);
    #pragma unroll 4
    for (int kq = 0; kq < 32; ++kq) {
      int k = kq*4;
      float4 wv = ldg4c<WT32>(wt, (size_t)cI*128 + k);
      float4 h = *(const float4*)&hL[r*128 + k];
      acc += wv.x*h.x + wv.y*h.y + wv.z*h.z + wv.w*h.w;
    }
    sjp += acc * ldr1(a, cI, f_a);
    sip += acc * ldr1(a, cI + 128, f_a);
  }
  redb[(r*16+cg)*2]   = sjp;
  redb[(r*16+cg)*2+1] = sip;
  __syncthreads();
  if (tid < 32) {
    int r2 = tid >> 1, wh = tid & 1;
    float s = 0.f;
    for (int g = 0; g < 16; ++g) s += redb[(r2*16+g)*2 + wh];
    if (wh == 0) sjg[r0+r2] = s; else sig[r0+r2] = s;
  }
}

__global__ __launch_bounds__(256) void sprep_kernel(
    const float* hidg, const void* wt, const void* bt, const void* a,
    float* sjg, float* sig)
{
  __shared__ float hL[2048];
  __shared__ float redb[512];
  __shared__ int sp;
  int f_wt = probe_f32(wt, 256, &sp);
  int f_bt = probe_f32(bt, 128, &sp);
  int f_a  = probe_f32(a,  256, &sp);
  if (f_wt) sprep_body<true >(hidg, wt, bt, a, f_bt, f_a, sjg, sig, hL, redb);
  else      sprep_body<false>(hidg, wt, bt, a, f_bt, f_a, sjg, sig, hL, redb);
}

// ---------------- MFMA attention + residual + MLP tail (validated R9) -----
template<bool PW32>
__device__ void attn_body(
    const float* sjg, const float* sig, const float* hidg,
    const unsigned short* hTh, const unsigned short* hTl,
    const void* wfc, const void* bfc, const void* wp1, const void* bp1,
    const void* wp2, const void* bp2,
    int f_bfc, int f_bp1, int f_wp2, float* outg,
    float* sjs, unsigned short* Pbuf, float* Obuf, float* redm,
    float* siL, float* miL, float* Zb)
{
  unsigned short* Phi = Pbuf;
  unsigned short* Plo = Pbuf + 8320;
  const int tid = threadIdx.x;
  const int w = tid >> 6, lane = tid & 63, ln = lane & 15, kq = lane >> 4;
  const int r0 = blockIdx.x * 16;

  for (int i = tid; i < 4096; i += 512) sjs[i] = sjg[i];
  __syncthreads();
  float mx = -1e30f;
  for (int i = tid; i < 4096; i += 512) mx = fmaxf(mx, sjs[i]);
  redm[tid] = mx;
  __syncthreads();
  for (int s = 256; s > 0; s >>= 1) {
    if (tid < s) redm[tid] = fmaxf(redm[tid], redm[tid+s]);
    __syncthreads();
  }
  if (tid < 16) {
    float si = sig[r0 + tid];
    siL[tid] = si;
    miL[tid] = lrelu(si + redm[0]);
  }
  __syncthreads();

  float zp[16];
  #pragma unroll
  for (int i = 0; i < 16; ++i) zp[i] = 0.f;
  f32x4 accO = f4zero();
  const int col = w*16 + ln;

  #pragma unroll 1
  for (int ch = 0; ch < 8; ++ch) {
    {
      float sjv = sjs[ch*512 + tid];
      #pragma unroll
      for (int i = 0; i < 16; ++i) {
        float v = lrelu(siL[i] + sjv);
        float p = __expf(v - miL[i]);
        zp[i] += p;
        unsigned short hh = f2b(p);
        Phi[i*520 + tid] = hh;
        Plo[i*520 + tid] = f2b(p - b2f(hh));
      }
    }
    __syncthreads();
    #pragma unroll
    for (int ks = 0; ks < 16; ++ks) {
      short8 Ah = *(const short8*)&Phi[ln*520 + ks*32 + kq*8];
      short8 Al = *(const short8*)&Plo[ln*520 + ks*32 + kq*8];
      size_t bo = (size_t)col*NB + ch*512 + ks*32 + kq*8;
      short8 Bh = *(const short8*)&hTh[bo];
      short8 Bl = *(const short8*)&hTl[bo];
      accO = MFMA(Ah, Bh, accO, 0,0,0);
      accO = MFMA(Ah, Bl, accO, 0,0,0);
      accO = MFMA(Al, Bh, accO, 0,0,0);
    }
    __syncthreads();
  }

  #pragma unroll
  for (int rg = 0; rg < 4; ++rg)
    Obuf[(kq*4+rg)*128 + col] = accO[rg];

  float* zarr = (float*)Pbuf;
  #pragma unroll
  for (int i = 0; i < 16; ++i) zarr[i*512 + tid] = zp[i];
  __syncthreads();
  {
    int row = tid >> 5, t0 = tid & 31;
    float s = 0.f;
    #pragma unroll
    for (int k = 0; k < 16; ++k) s += zarr[row*512 + t0 + 32*k];
    redm[row*32 + t0] = s;
  }
  __syncthreads();
  if (tid < 16) {
    float s = 0.f;
    for (int g = 0; g < 32; ++g) s += redm[tid*32 + g];
    Zb[tid] = s;
  }
  __syncthreads();

  {
    int e0 = tid*4, row = e0 >> 7, c = e0 & 127;
    float zi = Zb[row];
    #pragma unroll
    for (int e = 0; e < 4; ++e)
      Obuf[e0+e] = Obuf[e0+e]/zi + hidg[(size_t)(r0+row)*128 + c + e];
  }
  __syncthreads();

  float* h3f = sjs;
  {
    int o0 = tid*4, row = o0 >> 7, c = o0 & 127;
    #pragma unroll 1
    for (int e = 0; e < 4; ++e) {
      int cI = c + e;
      float acc = ldr1(bfc, cI, f_bfc);
      #pragma unroll 4
      for (int k4 = 0; k4 < 32; ++k4) {
        int k = k4*4;
        float4 wv = ldg4c<PW32>(wfc, (size_t)cI*128 + k);
        float4 h = *(const float4*)&Obuf[row*128 + k];
        acc += wv.x*h.x + wv.y*h.y + wv.z*h.z + wv.w*h.w;
      }
      h3f[row*128 + cI] = lrelu(acc);
    }
  }
  __syncthreads();

  float* h1f = (float*)Pbuf;
  {
    int o0 = tid*8, row = o0 >> 8, c = o0 & 255;
    #pragma unroll 1
    for (int e = 0; e < 8; ++e) {
      int cI = c + e;
      float acc = ldr1(bp1, cI, f_bp1);
      #pragma unroll 4
      for (int k4 = 0; k4 < 32; ++k4) {
        int k = k4*4;
        float4 wv = ldg4c<PW32>(wp1, (size_t)cI*128 + k);
        float4 h = *(const float4*)&h3f[row*128 + k];
        acc += wv.x*h.x + wv.y*h.y + wv.z*h.z + wv.w*h.w;
      }
      h1f[row*256 + cI] = 0.5f*acc*(1.0f + erff(acc*0.70710678118f));
    }
  }
  __syncthreads();

  {
    int row = tid >> 5, t0 = tid & 31;
    float s = 0.f;
    #pragma unroll
    for (int k = 0; k < 8; ++k) {
      int cI = t0 + 32*k;
      s += h1f[row*256 + cI] * ldr1(wp2, cI, f_wp2);
    }
    redm[row*32 + t0] = s;
  }
  __syncthreads();
  if (tid < 16) {
    float acc = ldr1(bp2, 0, f_bp1);
    for (int g = 0; g < 32; ++g) acc += redm[tid*32 + g];
    outg[r0 + tid] = acc;
  }
}

__global__ __launch_bounds__(512) void attn_kernel(
    const float* sjg, const float* sig, const float* hidg,
    const unsigned short* hTh, const unsigned short* hTl,
    const void* wfc, const void* bfc, const void* wp1, const void* bp1,
    const void* wp2, const void* bp2, float* outg)
{
  __shared__ float sjs[4096];
  __shared__ __align__(16) unsigned short Pbuf[16640];
  __shared__ float Obuf[2048];
  __shared__ float redm[512];
  __shared__ float siL[16], miL[16], Zb[16];
  __shared__ int sp;
  int f_wfc = probe_f32(wfc, 256, &sp);
  int f_bfc = probe_f32(bfc, 128, &sp);
  int f_bp1 = probe_f32(bp1, 256, &sp);
  int f_wp2 = probe_f32(wp2, 256, &sp);
  if (f_wfc) attn_body<true >(sjg, sig, hidg, hTh, hTl, wfc, bfc, wp1, bp1,
                              wp2, bp2, f_bfc, f_bp1, f_wp2, outg,
                              sjs, Pbuf, Obuf, redm, siL, miL, Zb);
  else       attn_body<false>(sjg, sig, hidg, hTh, hTl, wfc, bfc, wp1, bp1,
                              wp2, bp2, f_bfc, f_bp1, f_wp2, outg,
                              sjs, Pbuf, Obuf, redm, siL, miL, Zb);
}

extern "C" void kernel_launch(void* const* d_in, const int* in_sizes, int n_in,
                              void* d_out, int out_size, void* d_ws, size_t ws_size,
                              hipStream_t stream)
{
  float* out = (float*)d_out;
  const int expected[18] = {15728640,24576,49152,384,384,49152,49152,384,384,
                            16384,128,256,16384,128,32768,256,256,1};
  int bad = 0;
  if (n_in != 18 || out_size != 4096) bad = 1600;
  else for (int i = 0; i < 18; ++i) if (in_sizes[i] != expected[i]) { bad = 1600; break; }
  if (!bad && ws_size < (size_t)WS_BASE) bad = 1664;
  if (bad) { diag_kernel<<<16, 256, 0, stream>>>(out, (float)bad); return; }

  char* ws = (char*)d_ws;
  float*          sj  = (float*)(ws + WS_SJ);
  float*          si  = (float*)(ws + WS_SI);
  float*          hid = (float*)(ws + WS_HID);
  unsigned short* hTh = (unsigned short*)(ws + WS_HTH);
  unsigned short* hTl = (unsigned short*)(ws + WS_HTL);

  repack_kernel<<<256, 256, 0, stream>>>(d_in[1], d_in[2], d_in[5], d_in[6], ws);
  if (ws_size >= WS_FULL) {
    unsigned* y0p = (unsigned*)(ws + WS_Y0P);
    gru0_kernel<<<256, 512, 0, stream>>>(d_in[0], d_in[3], d_in[4], ws, y0p);
    gru1_kernel<<<256, 512, 0, stream>>>(d_in[7], d_in[8], ws, y0p,
                                         hid, hTh, hTl);
  } else {
    gru_fb_kernel<<<256, 512, 0, stream>>>(d_in[0], d_in[3], d_in[4],
                                           d_in[7], d_in[8], ws, hid, hTh, hTl);
  }
  sprep_kernel<<<256, 256, 0, stream>>>(hid, d_in[9], d_in[10], d_in[11], sj, si);
  attn_kernel<<<256, 512, 0, stream>>>(sj, si, hid, hTh, hTl,
                                       d_in[12], d_in[13], d_in[14], d_in[15],
                                       d_in[16], d_in[17], out);
}

// Round 13
// 611.425 us; speedup vs baseline: 2.0432x; 1.0046x over previous
//
#include <hip/hip_runtime.h>
#include <cstdint>
#include <cstddef>

#define TSTEPS 60
#define NB 4096
#define HD 128

typedef __attribute__((ext_vector_type(8))) short short8;
typedef __attribute__((ext_vector_type(4))) float f32x4;

// ---------------- workspace layout (byte offsets) ----------------
#define WS_SJ    0
#define WS_SI    16384
#define WS_HID   32768                 // 4096*128 f32 = 2 MB
#define WS_HTH   2129920               // hid^T hi bf16 [128][4096] = 1 MB
#define WS_HTL   3178496               // hid^T lo bf16 = 1 MB
#define WS_F0H   4227072               // wih0 hi frags 49152 B
#define WS_F0L   (WS_F0H+49152)
#define WS_FR0H  (WS_F0L+49152)        // whh0 hi 98304 B
#define WS_FR0L  (WS_FR0H+98304)
#define WS_FR1H  (WS_FR0L+98304)
#define WS_FR1L  (WS_FR1H+98304)
#define WS_FR2H  (WS_FR1L+98304)
#define WS_FR2L  (WS_FR2H+98304)
#define WS_BASE  (WS_FR2L+98304)
#define WS_Y0P   WS_BASE               // packed y0 (hi|lo) uint: 256*60*2048*4
#define WS_FULL  (WS_Y0P + 125829120ULL)

__device__ __forceinline__ float b2f(unsigned short h){ return __uint_as_float(((unsigned)h)<<16); }
__device__ __forceinline__ unsigned short f2b(float f){
  unsigned u = __float_as_uint(f);
  u = (u + 0x7FFFu + ((u>>16)&1u)) >> 16;
  return (unsigned short)u;
}
__device__ __forceinline__ float sigm(float x){ return 1.0f/(1.0f + __expf(-x)); }
__device__ __forceinline__ float tanhfast(float x){
  float xc = fminf(fmaxf(x,-15.0f),15.0f);
  float e = __expf(2.0f*xc);
  return (e-1.0f)/(e+1.0f);
}
__device__ __forceinline__ float lrelu(float x){ return x > 0.0f ? x : 0.01f*x; }
__device__ __forceinline__ float ldr1(const void* p, size_t i, int f32){
  return f32 ? ((const float*)p)[i] : b2f(((const unsigned short*)p)[i]);
}
template<bool F32>
__device__ __forceinline__ float4 ldg4c(const void* p, size_t i){
  if (F32) return *(const float4*)((const float*)p + i);
  ushort4 u = *(const ushort4*)((const unsigned short*)p + i);
  float4 f; f.x=b2f(u.x); f.y=b2f(u.y); f.z=b2f(u.z); f.w=b2f(u.w); return f;
}
__device__ __forceinline__ f32x4 f4zero(){ f32x4 v = {0.f,0.f,0.f,0.f}; return v; }
__device__ __forceinline__ void pinv(short8& v){ asm volatile("" : "+v"(v)); }

// LDS-only barrier: drains LDS (lgkmcnt) but leaves global loads/stores in
// flight (vs __syncthreads' full vmcnt(0) drain). Safe here: in-flight global
// stores (y0/hT) have no reader until the next kernel; in-flight global loads
// are register prefetches whose consumers get compiler-inserted vmcnt waits.
__device__ __forceinline__ void ldsbar(){
  asm volatile("s_waitcnt lgkmcnt(0)\n\ts_barrier" ::: "memory");
}

// Block-uniform dtype probe (validated R7/R8): 1 = fp32, 0 = bf16.
__device__ int probe_f32(const void* p, int nprobe, volatile int* s){
  if (threadIdx.x == 0) *s = 0;
  __syncthreads();
  if ((int)threadIdx.x < nprobe) {
    float v = b2f(((const unsigned short*)p)[threadIdx.x]);
    if (!(v == v) || fabsf(v) > 1e4f) *s = 1;
  }
  __syncthreads();
  int r = *s;
  __syncthreads();
  return r;
}

__global__ void diag_kernel(float* out, float code){
  int i = blockIdx.x*256 + threadIdx.x;
  if (i < 4096) out[i] = code;
}

// ---------------- weight repack (validated R8) ----------------------------
__device__ void repack_mat(const void* src, int f32, int K, int nks,
                           unsigned short* hi, unsigned short* lo,
                           int tid, int nthr){
  int total = 384*K;
  for (int idx = tid; idx < total; idx += nthr) {
    int j = idx & 7, lane = (idx>>3)&63, t = idx>>9;
    int ks = t % nks, g = (t/nks)%3, w = t/(nks*3);
    int row = 16*(w + 8*g) + (lane & 15);
    int k   = ks*32 + ((lane>>4)<<3) + j;
    float v = f32 ? ((const float*)src)[(size_t)row*K + k]
                  : b2f(((const unsigned short*)src)[(size_t)row*K + k]);
    unsigned short h = f2b(v);
    hi[idx] = h;
    lo[idx] = f2b(v - b2f(h));
  }
}

__global__ __launch_bounds__(256) void repack_kernel(
    const void* wih0, const void* whh0, const void* wih1, const void* whh1,
    char* ws)
{
  __shared__ int sp;
  int f0 = probe_f32(wih0, 256, &sp);
  int f1 = probe_f32(whh0, 256, &sp);
  int f2 = probe_f32(wih1, 256, &sp);
  int f3 = probe_f32(whh1, 256, &sp);
  int tid  = blockIdx.x*256 + threadIdx.x;
  int nthr = gridDim.x*256;
  repack_mat(wih0, f0,  64, 2, (unsigned short*)(ws+WS_F0H),  (unsigned short*)(ws+WS_F0L),  tid, nthr);
  repack_mat(whh0, f1, 128, 4, (unsigned short*)(ws+WS_FR0H), (unsigned short*)(ws+WS_FR0L), tid, nthr);
  repack_mat(wih1, f2, 128, 4, (unsigned short*)(ws+WS_FR1H), (unsigned short*)(ws+WS_FR1L), tid, nthr);
  repack_mat(whh1, f3, 128, 4, (unsigned short*)(ws+WS_FR2H), (unsigned short*)(ws+WS_FR2L), tid, nthr);
}

#define MFMA __builtin_amdgcn_mfma_f32_16x16x32_bf16

// ---------------- PHASE 0: layer-0 GRU, all 60 steps, 16 rows/block -------
// wih0 hi+lo in LDS; whh0 hi+lo PINNED (96 VGPR). x AND h double-buffered;
// ONE LDS-only barrier per step (no vmem drain).
__global__ __launch_bounds__(512) __attribute__((amdgpu_waves_per_eu(2,2)))
void gru0_kernel(const void* __restrict__ xg,
                 const void* __restrict__ bih0, const void* __restrict__ bhh0,
                 const char* __restrict__ ws, unsigned* __restrict__ y0p)
{
  __shared__ __align__(16) unsigned short wih0L[49152];          // hi | lo
  __shared__ __align__(16) unsigned short xbh[2][1152], xbl[2][1152];
  __shared__ __align__(16) unsigned short hbh[2][2176], hbl[2][2176];
  __shared__ int sp;
  const int tid  = threadIdx.x;
  const int w    = tid >> 6;
  const int lane = tid & 63;
  const int ln   = lane & 15;
  const int kq   = lane >> 4;
  const int r0   = blockIdx.x * 16;

  int xf  = probe_f32(xg,   256, &sp);
  int fb0 = probe_f32(bih0, 256, &sp);
  int fh0 = probe_f32(bhh0, 256, &sp);

  const unsigned short* f0h  = (const unsigned short*)(ws+WS_F0H);
  const unsigned short* f0l  = (const unsigned short*)(ws+WS_F0L);
  const unsigned short* fr0h = (const unsigned short*)(ws+WS_FR0H);
  const unsigned short* fr0l = (const unsigned short*)(ws+WS_FR0L);

  for (int i = tid*8; i < 24576; i += 4096) {
    *(ushort4*)&wih0L[i]         = *(const ushort4*)&f0h[i];
    *(ushort4*)&wih0L[i+4]       = *(const ushort4*)&f0h[i+4];
    *(ushort4*)&wih0L[24576+i]   = *(const ushort4*)&f0l[i];
    *(ushort4*)&wih0L[24576+i+4] = *(const ushort4*)&f0l[i+4];
  }

  short8 R0h[3][4], R0l[3][4];
  #pragma unroll
  for (int g = 0; g < 3; ++g)
    #pragma unroll
    for (int ks = 0; ks < 4; ++ks) {
      int fi = (w*3+g)*4 + ks;
      R0h[g][ks] = *(const short8*)&fr0h[fi*512 + lane*8];
      R0l[g][ks] = *(const short8*)&fr0l[fi*512 + lane*8];
      pinv(R0h[g][ks]); pinv(R0l[g][ks]);
    }

  const int nr = 16*w + ln;
  float brc0 = ldr1(bih0,nr,fb0)     + ldr1(bhh0,nr,fh0);
  float bzc0 = ldr1(bih0,nr+128,fb0) + ldr1(bhh0,nr+128,fh0);
  float bin0 = ldr1(bih0,nr+256,fb0);
  float bhn0 = ldr1(bhh0,nr+256,fh0);

  for (int i = tid; i < 2176; i += 512) { hbh[0][i] = 0; hbl[0][i] = 0; }
  const int xm = tid >> 5, xfc = (tid & 31)*2;
  {
    size_t base = ((size_t)(r0+xm)*TSTEPS + 0)*64 + xfc;
    float v0, v1;
    if (xf) { float2 xv = *(const float2*)((const float*)xg + base); v0 = xv.x; v1 = xv.y; }
    else { ushort2 u = *(const ushort2*)((const unsigned short*)xg + base); v0 = b2f(u.x); v1 = b2f(u.y); }
    unsigned short a0 = f2b(v0), a1 = f2b(v1);
    xbh[0][xm*72+xfc] = a0;              xbh[0][xm*72+xfc+1] = a1;
    xbl[0][xm*72+xfc] = f2b(v0-b2f(a0)); xbl[0][xm*72+xfc+1] = f2b(v1-b2f(a1));
  }
  float h0o[4] = {0.f,0.f,0.f,0.f};
  __syncthreads();

  #pragma unroll 1
  for (int t = 0; t < TSTEPS; ++t) {
    const int b0 = t & 1, b1 = b0 ^ 1;
    unsigned short pa0=0, pa1=0, pl0=0, pl1=0;
    if (t+1 < TSTEPS) {
      size_t base = ((size_t)(r0+xm)*TSTEPS + (t+1))*64 + xfc;
      float v0, v1;
      if (xf) { float2 xv = *(const float2*)((const float*)xg + base); v0 = xv.x; v1 = xv.y; }
      else { ushort2 u = *(const ushort2*)((const unsigned short*)xg + base); v0 = b2f(u.x); v1 = b2f(u.y); }
      pa0 = f2b(v0); pa1 = f2b(v1);
      pl0 = f2b(v0-b2f(pa0)); pl1 = f2b(v1-b2f(pa1));
    }

    f32x4 acc[4];
    #pragma unroll
    for (int g = 0; g < 4; ++g) acc[g] = f4zero();
    #pragma unroll
    for (int ks = 0; ks < 2; ++ks) {          // x part (LDS weights)
      short8 axh = *(const short8*)&xbh[b0][ln*72 + ks*32 + kq*8];
      short8 axl = *(const short8*)&xbl[b0][ln*72 + ks*32 + kq*8];
      #pragma unroll
      for (int g = 0; g < 3; ++g) {
        int fi = (w*3+g)*2 + ks;
        short8 bh = *(const short8*)&wih0L[fi*512 + lane*8];
        short8 bl = *(const short8*)&wih0L[24576 + fi*512 + lane*8];
        acc[g] = MFMA(axh, bh, acc[g], 0,0,0);
        acc[g] = MFMA(axh, bl, acc[g], 0,0,0);
        acc[g] = MFMA(axl, bh, acc[g], 0,0,0);
      }
    }
    #pragma unroll
    for (int ks = 0; ks < 4; ++ks) {          // h part (pinned weights)
      short8 ahh = *(const short8*)&hbh[b0][ln*136 + ks*32 + kq*8];
      short8 ahl = *(const short8*)&hbl[b0][ln*136 + ks*32 + kq*8];
      #pragma unroll
      for (int g = 0; g < 3; ++g) {
        int tgt = (g==2) ? 3 : g;
        acc[tgt] = MFMA(ahh, R0h[g][ks], acc[tgt], 0,0,0);
        acc[tgt] = MFMA(ahh, R0l[g][ks], acc[tgt], 0,0,0);
        acc[tgt] = MFMA(ahl, R0h[g][ks], acc[tgt], 0,0,0);
      }
    }
    unsigned short nh[4], nl[4];
    #pragma unroll
    for (int rg = 0; rg < 4; ++rg) {
      float r  = sigm(acc[0][rg] + brc0);
      float z  = sigm(acc[1][rg] + bzc0);
      float nn = tanhfast(acc[2][rg] + bin0 + r*(acc[3][rg] + bhn0));
      float h  = nn + z*(h0o[rg] - nn);
      h0o[rg] = h;
      unsigned short hh = f2b(h);
      nh[rg] = hh; nl[rg] = f2b(h - b2f(hh));
    }
    // y0 store: fire-and-forget (ldsbar does not drain it)
    {
      size_t ybase = ((size_t)blockIdx.x*TSTEPS + t)*2048;
      #pragma unroll
      for (int rg = 0; rg < 4; ++rg)
        y0p[ybase + (kq*4+rg)*128 + w*16 + ln] =
            (unsigned)nh[rg] | ((unsigned)nl[rg] << 16);
    }
    // write h(t+1) into the OTHER buffer (no WAR with step-t readers)
    #pragma unroll
    for (int rg = 0; rg < 4; ++rg) {
      int off = (kq*4+rg)*136 + w*16 + ln;
      hbh[b1][off] = nh[rg]; hbl[b1][off] = nl[rg];
    }
    if (t+1 < TSTEPS) {
      xbh[b1][xm*72+xfc] = pa0; xbh[b1][xm*72+xfc+1] = pa1;
      xbl[b1][xm*72+xfc] = pl0; xbl[b1][xm*72+xfc+1] = pl1;
    }
    ldsbar();          // single LDS-only barrier per step
  }
}

// ---------------- PHASE 1: layer-1 GRU, all 60 steps, 16 rows/block -------
// wih1-hi in LDS; wih1-lo + whh1 hi+lo PINNED (144 VGPR). y0 prefetched,
// y AND h double-buffered; ONE LDS-only barrier per step.
__global__ __launch_bounds__(512) __attribute__((amdgpu_waves_per_eu(2,2)))
void gru1_kernel(const void* __restrict__ bih1, const void* __restrict__ bhh1,
                 const char* __restrict__ ws, const unsigned* __restrict__ y0p,
                 float* __restrict__ hidg,
                 unsigned short* __restrict__ hTh, unsigned short* __restrict__ hTl)
{
  __shared__ __align__(16) unsigned short wih1hL[49152];         // hi only
  __shared__ __align__(16) unsigned short ybh[2][2176], ybl[2][2176];
  __shared__ __align__(16) unsigned short h1bh[2][2176], h1bl[2][2176];
  __shared__ int sp;
  const int tid  = threadIdx.x;
  const int w    = tid >> 6;
  const int lane = tid & 63;
  const int ln   = lane & 15;
  const int kq   = lane >> 4;
  const int r0   = blockIdx.x * 16;

  int fb1 = probe_f32(bih1, 256, &sp);
  int fh1 = probe_f32(bhh1, 256, &sp);

  const unsigned short* fr1h = (const unsigned short*)(ws+WS_FR1H);
  const unsigned short* fr1l = (const unsigned short*)(ws+WS_FR1L);
  const unsigned short* fr2h = (const unsigned short*)(ws+WS_FR2H);
  const unsigned short* fr2l = (const unsigned short*)(ws+WS_FR2L);

  for (int i = tid*8; i < 49152; i += 4096) {
    *(ushort4*)&wih1hL[i]   = *(const ushort4*)&fr1h[i];
    *(ushort4*)&wih1hL[i+4] = *(const ushort4*)&fr1h[i+4];
  }

  short8 W1l[3][4], R2h[3][4], R2l[3][4];
  #pragma unroll
  for (int g = 0; g < 3; ++g)
    #pragma unroll
    for (int ks = 0; ks < 4; ++ks) {
      int fi = (w*3+g)*4 + ks;
      W1l[g][ks] = *(const short8*)&fr1l[fi*512 + lane*8];
      R2h[g][ks] = *(const short8*)&fr2h[fi*512 + lane*8];
      R2l[g][ks] = *(const short8*)&fr2l[fi*512 + lane*8];
      pinv(W1l[g][ks]); pinv(R2h[g][ks]); pinv(R2l[g][ks]);
    }

  const int nr = 16*w + ln;
  float brc1 = ldr1(bih1,nr,fb1)     + ldr1(bhh1,nr,fh1);
  float bzc1 = ldr1(bih1,nr+128,fb1) + ldr1(bhh1,nr+128,fh1);
  float bin1 = ldr1(bih1,nr+256,fb1);
  float bhn1 = ldr1(bhh1,nr+256,fh1);

  for (int i = tid; i < 2176; i += 512) { h1bh[0][i] = 0; h1bl[0][i] = 0; }
  const int yi4 = tid*4, yrow = yi4 >> 7, ycol = yi4 & 127;
  {
    uint4 pv = *(const uint4*)&y0p[((size_t)blockIdx.x*TSTEPS + 0)*2048 + yi4];
    ushort4 vh, vl;
    vh.x=(unsigned short)(pv.x&0xffff); vl.x=(unsigned short)(pv.x>>16);
    vh.y=(unsigned short)(pv.y&0xffff); vl.y=(unsigned short)(pv.y>>16);
    vh.z=(unsigned short)(pv.z&0xffff); vl.z=(unsigned short)(pv.z>>16);
    vh.w=(unsigned short)(pv.w&0xffff); vl.w=(unsigned short)(pv.w>>16);
    *(ushort4*)&ybh[0][yrow*136+ycol] = vh;
    *(ushort4*)&ybl[0][yrow*136+ycol] = vl;
  }
  float h1o[4] = {0.f,0.f,0.f,0.f};
  __syncthreads();

  #pragma unroll 1
  for (int t = 0; t < TSTEPS; ++t) {
    const int b0 = t & 1, b1 = b0 ^ 1;
    uint4 pv = {0,0,0,0};
    if (t+1 < TSTEPS)
      pv = *(const uint4*)&y0p[((size_t)blockIdx.x*TSTEPS + (t+1))*2048 + yi4];

    f32x4 acc[4];
    #pragma unroll
    for (int g = 0; g < 4; ++g) acc[g] = f4zero();
    #pragma unroll
    for (int ks = 0; ks < 4; ++ks) {
      short8 ayh = *(const short8*)&ybh[b0][ln*136 + ks*32 + kq*8];
      short8 ayl = *(const short8*)&ybl[b0][ln*136 + ks*32 + kq*8];
      short8 a1h = *(const short8*)&h1bh[b0][ln*136 + ks*32 + kq*8];
      short8 a1l = *(const short8*)&h1bl[b0][ln*136 + ks*32 + kq*8];
      #pragma unroll
      for (int g = 0; g < 3; ++g) {
        int tgtI = (g==2) ? 2 : g;
        int tgtH = (g==2) ? 3 : g;
        short8 bh = *(const short8*)&wih1hL[((w*3+g)*4+ks)*512 + lane*8];
        acc[tgtI] = MFMA(ayh, bh,         acc[tgtI], 0,0,0);
        acc[tgtI] = MFMA(ayh, W1l[g][ks], acc[tgtI], 0,0,0);
        acc[tgtI] = MFMA(ayl, bh,         acc[tgtI], 0,0,0);
        acc[tgtH] = MFMA(a1h, R2h[g][ks], acc[tgtH], 0,0,0);
        acc[tgtH] = MFMA(a1h, R2l[g][ks], acc[tgtH], 0,0,0);
        acc[tgtH] = MFMA(a1l, R2h[g][ks], acc[tgtH], 0,0,0);
      }
    }
    unsigned short nh[4], nl[4];
    #pragma unroll
    for (int rg = 0; rg < 4; ++rg) {
      float r  = sigm(acc[0][rg] + brc1);
      float z  = sigm(acc[1][rg] + bzc1);
      float nn = tanhfast(acc[2][rg] + bin1 + r*(acc[3][rg] + bhn1));
      float h  = nn + z*(h1o[rg] - nn);
      h1o[rg] = h;
      unsigned short hh = f2b(h);
      nh[rg] = hh; nl[rg] = f2b(h - b2f(hh));
    }
    #pragma unroll
    for (int rg = 0; rg < 4; ++rg) {
      int off = (kq*4+rg)*136 + w*16 + ln;
      h1bh[b1][off] = nh[rg]; h1bl[b1][off] = nl[rg];
    }
    if (t+1 < TSTEPS) {
      ushort4 vh, vl;
      vh.x=(unsigned short)(pv.x&0xffff); vl.x=(unsigned short)(pv.x>>16);
      vh.y=(unsigned short)(pv.y&0xffff); vl.y=(unsigned short)(pv.y>>16);
      vh.z=(unsigned short)(pv.z&0xffff); vl.z=(unsigned short)(pv.z>>16);
      vh.w=(unsigned short)(pv.w&0xffff); vl.w=(unsigned short)(pv.w>>16);
      *(ushort4*)&ybh[b1][yrow*136+ycol] = vh;
      *(ushort4*)&ybl[b1][yrow*136+ycol] = vl;
    }
    ldsbar();          // single LDS-only barrier per step
  }

  // epilogue: hid (fp32) + hid^T hi/lo (bf16)
  {
    int c = w*16 + ln;
    #pragma unroll
    for (int rg = 0; rg < 4; ++rg)
      hidg[(size_t)(r0 + kq*4 + rg)*HD + c] = h1o[rg];
    ushort4 ph, pl;
    unsigned short* hh = (unsigned short*)&ph;
    unsigned short* ll = (unsigned short*)&pl;
    #pragma unroll
    for (int rg = 0; rg < 4; ++rg) {
      hh[rg] = f2b(h1o[rg]);
      ll[rg] = f2b(h1o[rg] - b2f(hh[rg]));
    }
    size_t o = (size_t)c*NB + r0 + kq*4;
    *(ushort4*)&hTh[o] = ph;
    *(ushort4*)&hTl[o] = pl;
  }
}

// ---------------- FALLBACK: R10 fused GRU (780 µs, proven) ----------------
__global__ __launch_bounds__(512, 1) void gru_fb_kernel(
    const void* __restrict__ xg,
    const void* __restrict__ bih0, const void* __restrict__ bhh0,
    const void* __restrict__ bih1, const void* __restrict__ bhh1,
    const char* __restrict__ ws, float* __restrict__ hidg,
    unsigned short* __restrict__ hTh, unsigned short* __restrict__ hTl)
{
  __shared__ __align__(16) unsigned short wih0L[49152];
  __shared__ __align__(16) unsigned short xhi[1152], xlo[1152];
  __shared__ __align__(16) unsigned short h0hi[2176], h0lo[2176];
  __shared__ __align__(16) unsigned short h1hi[2176], h1lo[2176];
  __shared__ int sp;
  const int tid  = threadIdx.x;
  const int w    = tid >> 6;
  const int lane = tid & 63;
  const int ln   = lane & 15;
  const int kq   = lane >> 4;
  const int r0   = blockIdx.x * 16;

  int xf  = probe_f32(xg,   256, &sp);
  int fb0 = probe_f32(bih0, 256, &sp);
  int fh0 = probe_f32(bhh0, 256, &sp);
  int fb1 = probe_f32(bih1, 256, &sp);
  int fh1 = probe_f32(bhh1, 256, &sp);

  const unsigned short* f0h  = (const unsigned short*)(ws+WS_F0H);
  const unsigned short* f0l  = (const unsigned short*)(ws+WS_F0L);
  const unsigned short* fr0h = (const unsigned short*)(ws+WS_FR0H);
  const unsigned short* fr0l = (const unsigned short*)(ws+WS_FR0L);
  const unsigned short* fr1h = (const unsigned short*)(ws+WS_FR1H);
  const unsigned short* fr1l = (const unsigned short*)(ws+WS_FR1L);
  const unsigned short* fr2h = (const unsigned short*)(ws+WS_FR2H);
  const unsigned short* fr2l = (const unsigned short*)(ws+WS_FR2L);

  for (int i = tid*8; i < 24576; i += 4096) {
    *(ushort4*)&wih0L[i]         = *(const ushort4*)&f0h[i];
    *(ushort4*)&wih0L[i+4]       = *(const ushort4*)&f0h[i+4];
    *(ushort4*)&wih0L[24576+i]   = *(const ushort4*)&f0l[i];
    *(ushort4*)&wih0L[24576+i+4] = *(const ushort4*)&f0l[i+4];
  }
  short8 R0h[3][4], R1h[3][4], R2h[3][4];
  #pragma unroll
  for (int g = 0; g < 3; ++g)
    #pragma unroll
    for (int ks = 0; ks < 4; ++ks) {
      int fi = (w*3+g)*4 + ks;
      R0h[g][ks] = *(const short8*)&fr0h[fi*512 + lane*8];
      R1h[g][ks] = *(const short8*)&fr1h[fi*512 + lane*8];
      R2h[g][ks] = *(const short8*)&fr2h[fi*512 + lane*8];
      pinv(R0h[g][ks]); pinv(R1h[g][ks]); pinv(R2h[g][ks]);
    }
  const int nr = 16*w + ln;
  float brc0 = ldr1(bih0,nr,fb0)     + ldr1(bhh0,nr,fh0);
  float bzc0 = ldr1(bih0,nr+128,fb0) + ldr1(bhh0,nr+128,fh0);
  float bin0 = ldr1(bih0,nr+256,fb0);
  float bhn0 = ldr1(bhh0,nr+256,fh0);
  float brc1 = ldr1(bih1,nr,fb1)     + ldr1(bhh1,nr,fh1);
  float bzc1 = ldr1(bih1,nr+128,fb1) + ldr1(bhh1,nr+128,fh1);
  float bin1 = ldr1(bih1,nr+256,fb1);
  float bhn1 = ldr1(bhh1,nr+256,fh1);

  for (int i = tid; i < 2176; i += 512) {
    h0hi[i] = 0; h0lo[i] = 0; h1hi[i] = 0; h1lo[i] = 0;
  }
  float h0o[4] = {0.f,0.f,0.f,0.f};
  float h1o[4] = {0.f,0.f,0.f,0.f};
  __syncthreads();

  #pragma unroll 1
  for (int t = 0; t < TSTEPS; ++t) {
    {
      int i0 = tid*2, m = i0 >> 6, f = i0 & 63;
      size_t base = ((size_t)(r0+m)*TSTEPS + t)*64 + f;
      float v0, v1;
      if (xf) { float2 xv = *(const float2*)((const float*)xg + base); v0 = xv.x; v1 = xv.y; }
      else { ushort2 u = *(const ushort2*)((const unsigned short*)xg + base); v0 = b2f(u.x); v1 = b2f(u.y); }
      unsigned short a0 = f2b(v0), a1 = f2b(v1);
      xhi[m*72+f] = a0;              xhi[m*72+f+1] = a1;
      xlo[m*72+f] = f2b(v0-b2f(a0)); xlo[m*72+f+1] = f2b(v1-b2f(a1));
    }
    __syncthreads();
    f32x4 acc[4];
    #pragma unroll
    for (int g = 0; g < 4; ++g) acc[g] = f4zero();
    #pragma unroll
    for (int ks = 0; ks < 2; ++ks) {
      short8 axh = *(const short8*)&xhi[ln*72 + ks*32 + kq*8];
      short8 axl = *(const short8*)&xlo[ln*72 + ks*32 + kq*8];
      #pragma unroll
      for (int g = 0; g < 3; ++g) {
        int fi = (w*3+g)*2 + ks;
        short8 bh = *(const short8*)&wih0L[fi*512 + lane*8];
        short8 bl = *(const short8*)&wih0L[24576 + fi*512 + lane*8];
        acc[g] = MFMA(axh, bh, acc[g], 0,0,0);
        acc[g] = MFMA(axh, bl, acc[g], 0,0,0);
        acc[g] = MFMA(axl, bh, acc[g], 0,0,0);
      }
    }
    #pragma unroll
    for (int ks = 0; ks < 4; ++ks) {
      short8 ahh = *(const short8*)&h0hi[ln*136 + ks*32 + kq*8];
      short8 ahl = *(const short8*)&h0lo[ln*136 + ks*32 + kq*8];
      #pragma unroll
      for (int g = 0; g < 3; ++g) {
        int tgt = (g==2) ? 3 : g;
        short8 bl = *(const short8*)&fr0l[((w*3+g)*4+ks)*512 + lane*8];
        acc[tgt] = MFMA(ahh, R0h[g][ks], acc[tgt], 0,0,0);
        acc[tgt] = MFMA(ahh, bl,         acc[tgt], 0,0,0);
        acc[tgt] = MFMA(ahl, R0h[g][ks], acc[tgt], 0,0,0);
      }
    }
    unsigned short nh[4], nl[4];
    #pragma unroll
    for (int rg = 0; rg < 4; ++rg) {
      float r  = sigm(acc[0][rg] + brc0);
      float z  = sigm(acc[1][rg] + bzc0);
      float nn = tanhfast(acc[2][rg] + bin0 + r*(acc[3][rg] + bhn0));
      float h  = nn + z*(h0o[rg] - nn);
      h0o[rg] = h;
      unsigned short hh = f2b(h);
      nh[rg] = hh; nl[rg] = f2b(h - b2f(hh));
    }
    __syncthreads();
    #pragma unroll
    for (int rg = 0; rg < 4; ++rg) {
      int off = (kq*4+rg)*136 + w*16 + ln;
      h0hi[off] = nh[rg]; h0lo[off] = nl[rg];
    }
    __syncthreads();
    #pragma unroll
    for (int g = 0; g < 4; ++g) acc[g] = f4zero();
    #pragma unroll
    for (int ks = 0; ks < 4; ++ks) {
      short8 ayh = *(const short8*)&h0hi[ln*136 + ks*32 + kq*8];
      short8 ayl = *(const short8*)&h0lo[ln*136 + ks*32 + kq*8];
      short8 a1h = *(const short8*)&h1hi[ln*136 + ks*32 + kq*8];
      short8 a1l = *(const short8*)&h1lo[ln*136 + ks*32 + kq*8];
      #pragma unroll
      for (int g = 0; g < 3; ++g) {
        int tgtI = (g==2) ? 2 : g;
        int tgtH = (g==2) ? 3 : g;
        short8 blI = *(const short8*)&fr1l[((w*3+g)*4+ks)*512 + lane*8];
        short8 blH = *(const short8*)&fr2l[((w*3+g)*4+ks)*512 + lane*8];
        acc[tgtI] = MFMA(ayh, R1h[g][ks], acc[tgtI], 0,0,0);
        acc[tgtI] = MFMA(ayh, blI,        acc[tgtI], 0,0,0);
        acc[tgtI] = MFMA(ayl, R1h[g][ks], acc[tgtI], 0,0,0);
        acc[tgtH] = MFMA(a1h, R2h[g][ks], acc[tgtH], 0,0,0);
        acc[tgtH] = MFMA(a1h, blH,        acc[tgtH], 0,0,0);
        acc[tgtH] = MFMA(a1l, R2h[g][ks], acc[tgtH], 0,0,0);
      }
    }
    #pragma unroll
    for (int rg = 0; rg < 4; ++rg) {
      float r  = sigm(acc[0][rg] + brc1);
      float z  = sigm(acc[1][rg] + bzc1);
      float nn = tanhfast(acc[2][rg] + bin1 + r*(acc[3][rg] + bhn1));
      float h  = nn + z*(h1o[rg] - nn);
      h1o[rg] = h;
      unsigned short hh = f2b(h);
      nh[rg] = hh; nl[rg] = f2b(h - b2f(hh));
    }
    __syncthreads();
    #pragma unroll
    for (int rg = 0; rg < 4; ++rg) {
      int off = (kq*4+rg)*136 + w*16 + ln;
      h1hi[off] = nh[rg]; h1lo[off] = nl[rg];
    }
  }
  {
    int c = w*16 + ln;
    #pragma unroll
    for (int rg = 0; rg < 4; ++rg)
      hidg[(size_t)(r0 + kq*4 + rg)*HD + c] = h1o[rg];
    ushort4 ph, pl;
    unsigned short* hh = (unsigned short*)&ph;
    unsigned short* ll = (unsigned short*)&pl;
    #pragma unroll
    for (int rg = 0; rg < 4; ++rg) {
      hh[rg] = f2b(h1o[rg]);
      ll[rg] = f2b(h1o[rg] - b2f(hh[rg]));
    }
    size_t o = (size_t)c*NB + r0 + kq*4;
    *(ushort4*)&hTh[o] = ph;
    *(ushort4*)&hTl[o] = pl;
  }
}

// ---------------- s_j / s_i prep (fp32), 256 threads (validated R8) -------
template<bool WT32>
__device__ void sprep_body(
    const float* hidg, const void* wt, const void* bt, const void* a,
    int f_bt, int f_a, float* sjg, float* sig, float* hL, float* redb)
{
  const int tid = threadIdx.x;
  const int r0  = blockIdx.x * 16;
  for (int i = tid; i < 2048; i += 256) hL[i] = hidg[(size_t)r0*128 + i];
  __syncthreads();
  const int r = tid >> 4, cg = tid & 15, c0 = cg*8;
  float sjp = 0.f, sip = 0.f;
  #pragma unroll 1
  for (int cc = 0; cc < 8; ++cc) {
    int cI = c0 + cc;
    float acc = ldr1(bt, cI, f_bt);
    #pragma unroll 4
    for (int kq = 0; kq < 32; ++kq) {
      int k = kq*4;
      float4 wv = ldg4c<WT32>(wt, (size_t)cI*128 + k);
      float4 h = *(const float4*)&hL[r*128 + k];
      acc += wv.x*h.x + wv.y*h.y + wv.z*h.z + wv.w*h.w;
    }
    sjp += acc * ldr1(a, cI, f_a);
    sip += acc * ldr1(a, cI + 128, f_a);
  }
  redb[(r*16+cg)*2]   = sjp;
  redb[(r*16+cg)*2+1] = sip;
  __syncthreads();
  if (tid < 32) {
    int r2 = tid >> 1, wh = tid & 1;
    float s = 0.f;
    for (int g = 0; g < 16; ++g) s += redb[(r2*16+g)*2 + wh];
    if (wh == 0) sjg[r0+r2] = s; else sig[r0+r2] = s;
  }
}

__global__ __launch_bounds__(256) void sprep_kernel(
    const float* hidg, const void* wt, const void* bt, const void* a,
    float* sjg, float* sig)
{
  __shared__ float hL[2048];
  __shared__ float redb[512];
  __shared__ int sp;
  int f_wt = probe_f32(wt, 256, &sp);
  int f_bt = probe_f32(bt, 128, &sp);
  int f_a  = probe_f32(a,  256, &sp);
  if (f_wt) sprep_body<true >(hidg, wt, bt, a, f_bt, f_a, sjg, sig, hL, redb);
  else      sprep_body<false>(hidg, wt, bt, a, f_bt, f_a, sjg, sig, hL, redb);
}

// ---------------- MFMA attention + residual + MLP tail (validated R9) -----
template<bool PW32>
__device__ void attn_body(
    const float* sjg, const float* sig, const float* hidg,
    const unsigned short* hTh, const unsigned short* hTl,
    const void* wfc, const void* bfc, const void* wp1, const void* bp1,
    const void* wp2, const void* bp2,
    int f_bfc, int f_bp1, int f_wp2, float* outg,
    float* sjs, unsigned short* Pbuf, float* Obuf, float* redm,
    float* siL, float* miL, float* Zb)
{
  unsigned short* Phi = Pbuf;
  unsigned short* Plo = Pbuf + 8320;
  const int tid = threadIdx.x;
  const int w = tid >> 6, lane = tid & 63, ln = lane & 15, kq = lane >> 4;
  const int r0 = blockIdx.x * 16;

  for (int i = tid; i < 4096; i += 512) sjs[i] = sjg[i];
  __syncthreads();
  float mx = -1e30f;
  for (int i = tid; i < 4096; i += 512) mx = fmaxf(mx, sjs[i]);
  redm[tid] = mx;
  __syncthreads();
  for (int s = 256; s > 0; s >>= 1) {
    if (tid < s) redm[tid] = fmaxf(redm[tid], redm[tid+s]);
    __syncthreads();
  }
  if (tid < 16) {
    float si = sig[r0 + tid];
    siL[tid] = si;
    miL[tid] = lrelu(si + redm[0]);
  }
  __syncthreads();

  float zp[16];
  #pragma unroll
  for (int i = 0; i < 16; ++i) zp[i] = 0.f;
  f32x4 accO = f4zero();
  const int col = w*16 + ln;

  #pragma unroll 1
  for (int ch = 0; ch < 8; ++ch) {
    {
      float sjv = sjs[ch*512 + tid];
      #pragma unroll
      for (int i = 0; i < 16; ++i) {
        float v = lrelu(siL[i] + sjv);
        float p = __expf(v - miL[i]);
        zp[i] += p;
        unsigned short hh = f2b(p);
        Phi[i*520 + tid] = hh;
        Plo[i*520 + tid] = f2b(p - b2f(hh));
      }
    }
    __syncthreads();
    #pragma unroll
    for (int ks = 0; ks < 16; ++ks) {
      short8 Ah = *(const short8*)&Phi[ln*520 + ks*32 + kq*8];
      short8 Al = *(const short8*)&Plo[ln*520 + ks*32 + kq*8];
      size_t bo = (size_t)col*NB + ch*512 + ks*32 + kq*8;
      short8 Bh = *(const short8*)&hTh[bo];
      short8 Bl = *(const short8*)&hTl[bo];
      accO = MFMA(Ah, Bh, accO, 0,0,0);
      accO = MFMA(Ah, Bl, accO, 0,0,0);
      accO = MFMA(Al, Bh, accO, 0,0,0);
    }
    __syncthreads();
  }

  #pragma unroll
  for (int rg = 0; rg < 4; ++rg)
    Obuf[(kq*4+rg)*128 + col] = accO[rg];

  float* zarr = (float*)Pbuf;
  #pragma unroll
  for (int i = 0; i < 16; ++i) zarr[i*512 + tid] = zp[i];
  __syncthreads();
  {
    int row = tid >> 5, t0 = tid & 31;
    float s = 0.f;
    #pragma unroll
    for (int k = 0; k < 16; ++k) s += zarr[row*512 + t0 + 32*k];
    redm[row*32 + t0] = s;
  }
  __syncthreads();
  if (tid < 16) {
    float s = 0.f;
    for (int g = 0; g < 32; ++g) s += redm[tid*32 + g];
    Zb[tid] = s;
  }
  __syncthreads();

  {
    int e0 = tid*4, row = e0 >> 7, c = e0 & 127;
    float zi = Zb[row];
    #pragma unroll
    for (int e = 0; e < 4; ++e)
      Obuf[e0+e] = Obuf[e0+e]/zi + hidg[(size_t)(r0+row)*128 + c + e];
  }
  __syncthreads();

  float* h3f = sjs;
  {
    int o0 = tid*4, row = o0 >> 7, c = o0 & 127;
    #pragma unroll 1
    for (int e = 0; e < 4; ++e) {
      int cI = c + e;
      float acc = ldr1(bfc, cI, f_bfc);
      #pragma unroll 4
      for (int k4 = 0; k4 < 32; ++k4) {
        int k = k4*4;
        float4 wv = ldg4c<PW32>(wfc, (size_t)cI*128 + k);
        float4 h = *(const float4*)&Obuf[row*128 + k];
        acc += wv.x*h.x + wv.y*h.y + wv.z*h.z + wv.w*h.w;
      }
      h3f[row*128 + cI] = lrelu(acc);
    }
  }
  __syncthreads();

  float* h1f = (float*)Pbuf;
  {
    int o0 = tid*8, row = o0 >> 8, c = o0 & 255;
    #pragma unroll 1
    for (int e = 0; e < 8; ++e) {
      int cI = c + e;
      float acc = ldr1(bp1, cI, f_bp1);
      #pragma unroll 4
      for (int k4 = 0; k4 < 32; ++k4) {
        int k = k4*4;
        float4 wv = ldg4c<PW32>(wp1, (size_t)cI*128 + k);
        float4 h = *(const float4*)&h3f[row*128 + k];
        acc += wv.x*h.x + wv.y*h.y + wv.z*h.z + wv.w*h.w;
      }
      h1f[row*256 + cI] = 0.5f*acc*(1.0f + erff(acc*0.70710678118f));
    }
  }
  __syncthreads();

  {
    int row = tid >> 5, t0 = tid & 31;
    float s = 0.f;
    #pragma unroll
    for (int k = 0; k < 8; ++k) {
      int cI = t0 + 32*k;
      s += h1f[row*256 + cI] * ldr1(wp2, cI, f_wp2);
    }
    redm[row*32 + t0] = s;
  }
  __syncthreads();
  if (tid < 16) {
    float acc = ldr1(bp2, 0, f_bp1);
    for (int g = 0; g < 32; ++g) acc += redm[tid*32 + g];
    outg[r0 + tid] = acc;
  }
}

__global__ __launch_bounds__(512) void attn_kernel(
    const float* sjg, const float* sig, const float* hidg,
    const unsigned short* hTh, const unsigned short* hTl,
    const void* wfc, const void* bfc, const void* wp1, const void* bp1,
    const void* wp2, const void* bp2, float* outg)
{
  __shared__ float sjs[4096];
  __shared__ __align__(16) unsigned short Pbuf[16640];
  __shared__ float Obuf[2048];
  __shared__ float redm[512];
  __shared__ float siL[16], miL[16], Zb[16];
  __shared__ int sp;
  int f_wfc = probe_f32(wfc, 256, &sp);
  int f_bfc = probe_f32(bfc, 128, &sp);
  int f_bp1 = probe_f32(bp1, 256, &sp);
  int f_wp2 = probe_f32(wp2, 256, &sp);
  if (f_wfc) attn_body<true >(sjg, sig, hidg, hTh, hTl, wfc, bfc, wp1, bp1,
                              wp2, bp2, f_bfc, f_bp1, f_wp2, outg,
                              sjs, Pbuf, Obuf, redm, siL, miL, Zb);
  else       attn_body<false>(sjg, sig, hidg, hTh, hTl, wfc, bfc, wp1, bp1,
                              wp2, bp2, f_bfc, f_bp1, f_wp2, outg,
                              sjs, Pbuf, Obuf, redm, siL, miL, Zb);
}

extern "C" void kernel_launch(void* const* d_in, const int* in_sizes, int n_in,
                              void* d_out, int out_size, void* d_ws, size_t ws_size,
                              hipStream_t stream)
{
  float* out = (float*)d_out;
  const int expected[18] = {15728640,24576,49152,384,384,49152,49152,384,384,
                            16384,128,256,16384,128,32768,256,256,1};
  int bad = 0;
  if (n_in != 18 || out_size != 4096) bad = 1600;
  else for (int i = 0; i < 18; ++i) if (in_sizes[i] != expected[i]) { bad = 1600; break; }
  if (!bad && ws_size < (size_t)WS_BASE) bad = 1664;
  if (bad) { diag_kernel<<<16, 256, 0, stream>>>(out, (float)bad); return; }

  char* ws = (char*)d_ws;
  float*          sj  = (float*)(ws + WS_SJ);
  float*          si  = (float*)(ws + WS_SI);
  float*          hid = (float*)(ws + WS_HID);
  unsigned short* hTh = (unsigned short*)(ws + WS_HTH);
  unsigned short* hTl = (unsigned short*)(ws + WS_HTL);

  repack_kernel<<<256, 256, 0, stream>>>(d_in[1], d_in[2], d_in[5], d_in[6], ws);
  if (ws_size >= WS_FULL) {
    unsigned* y0p = (unsigned*)(ws + WS_Y0P);
    gru0_kernel<<<256, 512, 0, stream>>>(d_in[0], d_in[3], d_in[4], ws, y0p);
    gru1_kernel<<<256, 512, 0, stream>>>(d_in[7], d_in[8], ws, y0p,
                                         hid, hTh, hTl);
  } else {
    gru_fb_kernel<<<256, 512, 0, stream>>>(d_in[0], d_in[3], d_in[4],
                                           d_in[7], d_in[8], ws, hid, hTh, hTl);
  }
  sprep_kernel<<<256, 256, 0, stream>>>(hid, d_in[9], d_in[10], d_in[11], sj, si);
  attn_kernel<<<256, 512, 0, stream>>>(sj, si, hid, hTh, hTl,
                                       d_in[12], d_in[13], d_in[14], d_in[15],
                                       d_in[16], d_in[17], out);
}